// Round 1
// 1076.346 us; speedup vs baseline: 1.2607x; 1.2607x over previous
//
#include <hip/hip_runtime.h>
#include <math.h>

#define B_ 32
#define T_ 2048
#define N_ 2048
#define D_ 512
#define L_ 256
#define TE_ 1024
#define H_ 8
#define MROWS 65536  // B*T = B*N
#define KCH 16       // n-chunks for kstats partial reduction

typedef __attribute__((ext_vector_type(8))) short short8;
typedef __attribute__((ext_vector_type(4))) float f32x4;

__device__ __forceinline__ unsigned short f2bf(float f) {
  unsigned u = __float_as_uint(f);
  unsigned r = (u + 0x7FFF + ((u >> 16) & 1)) >> 16;  // RNE
  return (unsigned short)r;
}
__device__ __forceinline__ float bf2f(unsigned short u) {
  return __uint_as_float(((unsigned)u) << 16);
}
__device__ __forceinline__ void gload_lds16(const void* g, void* l) {
  __builtin_amdgcn_global_load_lds(
      (const __attribute__((address_space(1))) void*)g,
      (__attribute__((address_space(3))) void*)l, 16, 0, 0);
}

// ---------------- block reduce (256 threads) ----------------
__device__ __forceinline__ float blockReduceSum(float v, float* ws) {
#pragma unroll
  for (int m = 32; m >= 1; m >>= 1) v += __shfl_xor(v, m, 64);
  int wid = threadIdx.x >> 6;
  int lane = threadIdx.x & 63;
  __syncthreads();
  if (lane == 0) ws[wid] = v;
  __syncthreads();
  return ws[0] + ws[1] + ws[2] + ws[3];
}

// ---------------- row LayerNorm -> bf16 ----------------
template <int COLS>
__global__ void __launch_bounds__(256) ln_rows(const float* __restrict__ in,
                                               const float* __restrict__ g,
                                               const float* __restrict__ bb,
                                               unsigned short* __restrict__ out) {
  constexpr int E = COLS / 256;
  __shared__ float ws[4];
  size_t row = blockIdx.x;
  const float* rp = in + row * COLS;
  float v[E];
  float s = 0.f;
#pragma unroll
  for (int e = 0; e < E; ++e) {
    v[e] = rp[threadIdx.x + e * 256];
    s += v[e];
  }
  s = blockReduceSum(s, ws);
  float mean = s * (1.0f / COLS);
  float q = 0.f;
#pragma unroll
  for (int e = 0; e < E; ++e) {
    float d = v[e] - mean;
    q += d * d;
  }
  q = blockReduceSum(q, ws);
  float rstd = rsqrtf(q * (1.0f / COLS) + 1e-5f);
  unsigned short* op = out + row * COLS;
#pragma unroll
  for (int e = 0; e < E; ++e) {
    int c = threadIdx.x + e * 256;
    op[c] = f2bf((v[e] - mean) * rstd * g[c] + bb[c]);
  }
}

// ---------------- weight transpose + cast: Wt[n][k] = bf16(W[k][n]) ----------------
__global__ void __launch_bounds__(256) transcast(const float* __restrict__ W,
                                                 unsigned short* __restrict__ Wt,
                                                 int K, int Ncols) {
  __shared__ float t[32][33];
  int k0 = blockIdx.x * 32, n0 = blockIdx.y * 32;
  int tx = threadIdx.x & 31, ty = threadIdx.x >> 5;  // 32 x 8
#pragma unroll
  for (int i = 0; i < 32; i += 8)
    t[ty + i][tx] = W[(size_t)(k0 + ty + i) * Ncols + n0 + tx];
  __syncthreads();
#pragma unroll
  for (int i = 0; i < 32; i += 8)
    Wt[(size_t)(n0 + ty + i) * K + k0 + tx] = f2bf(t[tx][ty + i]);
}

// ---------------- bf16 MFMA GEMM: C[M,512] = A[M,KT] @ Wt[512,KT]^T + bias (+add) ----------------
// 128x128 tile, 4 waves in 2x2, each wave 64x64 as 4x4 of 16x16x32 MFMA.
template <int KT, bool ADD, bool OUTBF>
__global__ void __launch_bounds__(256) gemm_mfma(const unsigned short* __restrict__ A,
                                                 const unsigned short* __restrict__ Wt,
                                                 const float* __restrict__ bias,
                                                 const float* __restrict__ add,
                                                 void* __restrict__ Cv) {
  __shared__ __align__(16) unsigned short sA[128 * 32];
  __shared__ __align__(16) unsigned short sB[128 * 32];
  int tid = threadIdx.x;
  int w = tid >> 6, lane = tid & 63;
  int quad = lane >> 4, r16 = lane & 15;
  int wr = w >> 1, wc = w & 1;
  size_t m0 = (size_t)blockIdx.y * 128;
  int n0 = blockIdx.x * 128;
  int srow = lane >> 2;        // 0..15
  int scol = (lane & 3) * 8;   // ushort offset within 32-wide K slice
  f32x4 acc[4][4] = {};

  for (int k0 = 0; k0 < KT; k0 += 32) {
    __syncthreads();  // previous compute must finish before LDS overwrite
#pragma unroll
    for (int i = 0; i < 2; ++i) {
      int seg = w * 2 + i;  // 0..7, 16 rows each
      gload_lds16(&A[(m0 + seg * 16 + srow) * KT + k0 + scol], &sA[seg * 512]);
    }
#pragma unroll
    for (int i = 0; i < 2; ++i) {
      int seg = w * 2 + i;
      gload_lds16(&Wt[(size_t)(n0 + seg * 16 + srow) * KT + k0 + scol], &sB[seg * 512]);
    }
    __syncthreads();  // compiler drains vmcnt here (global_load_lds done)
    short8 af[4], bfr[4];
#pragma unroll
    for (int mi = 0; mi < 4; ++mi)
      af[mi] = *(const short8*)&sA[(wr * 64 + mi * 16 + r16) * 32 + quad * 8];
#pragma unroll
    for (int ni = 0; ni < 4; ++ni)
      bfr[ni] = *(const short8*)&sB[(wc * 64 + ni * 16 + r16) * 32 + quad * 8];
#pragma unroll
    for (int mi = 0; mi < 4; ++mi)
#pragma unroll
      for (int ni = 0; ni < 4; ++ni)
        acc[mi][ni] = __builtin_amdgcn_mfma_f32_16x16x32_bf16(af[mi], bfr[ni], acc[mi][ni], 0, 0, 0);
  }

  float* Cf = (float*)Cv;
  unsigned short* Cb = (unsigned short*)Cv;
#pragma unroll
  for (int mi = 0; mi < 4; ++mi)
#pragma unroll
    for (int r = 0; r < 4; ++r) {
      size_t grow = m0 + wr * 64 + mi * 16 + quad * 4 + r;
#pragma unroll
      for (int ni = 0; ni < 4; ++ni) {
        int gcol = n0 + wc * 64 + ni * 16 + r16;
        float val = acc[mi][ni][r] + bias[gcol];
        if constexpr (ADD) val += add[grow * 512 + gcol];
        if constexpr (OUTBF)
          Cb[grow * 512 + gcol] = f2bf(val);
        else
          Cf[grow * 512 + gcol] = val;
      }
    }
}

// ---------------- softmax over contiguous 64-groups (q, bf16 in/out) ----------------
__global__ void __launch_bounds__(256) qsoftmax(unsigned short* __restrict__ q) {
  size_t w = (size_t)blockIdx.x * 4 + (threadIdx.x >> 6);
  int lane = threadIdx.x & 63;
  size_t idx = w * 64 + lane;
  float v = bf2f(q[idx]);
  float m = v;
#pragma unroll
  for (int s = 32; s >= 1; s >>= 1) m = fmaxf(m, __shfl_xor(m, s, 64));
  float e = expf(v - m);
  float ssum = e;
#pragma unroll
  for (int s = 32; s >= 1; s >>= 1) ssum += __shfl_xor(ssum, s, 64);
  q[idx] = f2bf(e / ssum);
}

// ---------------- k softmax partial stats over an n-chunk (per b, channel) ----------------
// grid (B, D/64, KCH); each thread buffers its 32 values in registers (32
// independent loads in flight), computes max then sum-of-exp.
__global__ void __launch_bounds__(256) kstats_part(const float* __restrict__ k,
                                                   float* __restrict__ pmax,
                                                   float* __restrict__ psum) {
  int b = blockIdx.x, cg = blockIdx.y, ch = blockIdx.z;
  int tid = threadIdx.x;
  int lane = tid & 63, slice = tid >> 6;  // 4 slices over rows
  int c = cg * 64 + lane;
  constexpr int ROWS = N_ / KCH;          // 128
  constexpr int PT = ROWS / 4;            // 32 values per thread
  const float* kp = k + ((size_t)b * N_ + (size_t)ch * ROWS) * D_ + c;
  float v[PT];
#pragma unroll
  for (int i = 0; i < PT; ++i) v[i] = kp[(size_t)(slice + i * 4) * D_];
  float m = v[0];
#pragma unroll
  for (int i = 1; i < PT; ++i) m = fmaxf(m, v[i]);
  float s = 0.f;
#pragma unroll
  for (int i = 0; i < PT; ++i) s += expf(v[i] - m);
  // combine 4 slices per channel via LDS
  __shared__ float mred[256], sred[256];
  mred[tid] = m;
  sred[tid] = s;
  __syncthreads();
  if (tid < 64) {
    float m0 = mred[tid], m1 = mred[tid + 64], m2 = mred[tid + 128], m3 = mred[tid + 192];
    float mm = fmaxf(fmaxf(m0, m1), fmaxf(m2, m3));
    float ss = sred[tid] * expf(m0 - mm) + sred[tid + 64] * expf(m1 - mm) +
               sred[tid + 128] * expf(m2 - mm) + sred[tid + 192] * expf(m3 - mm);
    pmax[((size_t)b * KCH + ch) * D_ + cg * 64 + tid] = mm;
    psum[((size_t)b * KCH + ch) * D_ + cg * 64 + tid] = ss;
  }
}

// ---------------- combine KCH partial stats -> kmax/ksum ----------------
__global__ void __launch_bounds__(256) kstats_comb(const float* __restrict__ pmax,
                                                   const float* __restrict__ psum,
                                                   float* __restrict__ kmax,
                                                   float* __restrict__ ksum) {
  int b = blockIdx.x;
  int c = blockIdx.y * 256 + threadIdx.x;
  float pm[KCH];
#pragma unroll
  for (int ch = 0; ch < KCH; ++ch) pm[ch] = pmax[((size_t)b * KCH + ch) * D_ + c];
  float m = pm[0];
#pragma unroll
  for (int ch = 1; ch < KCH; ++ch) m = fmaxf(m, pm[ch]);
  float s = 0.f;
#pragma unroll
  for (int ch = 0; ch < KCH; ++ch)
    s += psum[((size_t)b * KCH + ch) * D_ + c] * expf(pm[ch] - m);
  kmax[b * D_ + c] = m;
  ksum[b * D_ + c] = s;
}

// ---------------- attn[b,h] += Kx^T @ V over an n-chunk of 256 ----------------
__global__ void __launch_bounds__(256) attn_kernel(const float* __restrict__ k,
                                                   const float* __restrict__ v,
                                                   const float* __restrict__ kmax,
                                                   const float* __restrict__ ksum,
                                                   float* __restrict__ attn) {
  int b = blockIdx.x, h = blockIdx.y, nc = blockIdx.z;
  int tid = threadIdx.x;
  __shared__ float ks_[32][68];
  __shared__ float vs_[32][68];
  __shared__ float mx[64], is_[64];
  if (tid < 64) {
    mx[tid] = kmax[b * D_ + h * 64 + tid];
    is_[tid] = 1.f / ksum[b * D_ + h * 64 + tid];
  }
  const float* kp = k + ((size_t)b * N_ + nc * 256) * D_ + h * 64;
  const float* vp = v + ((size_t)b * N_ + nc * 256) * D_ + h * 64;
  float acc[4][4] = {};
  int tx = tid & 15, ty = tid >> 4;
  int lr = tid >> 4;
  int c4 = (tid & 15) * 4;
  for (int n0 = 0; n0 < 256; n0 += 32) {
    __syncthreads();
#pragma unroll
    for (int rr = 0; rr < 32; rr += 16) {
      float4 kv = *(const float4*)&kp[(size_t)(n0 + lr + rr) * D_ + c4];
      float4 vv = *(const float4*)&vp[(size_t)(n0 + lr + rr) * D_ + c4];
      ks_[lr + rr][c4 + 0] = expf(kv.x - mx[c4 + 0]) * is_[c4 + 0];
      ks_[lr + rr][c4 + 1] = expf(kv.y - mx[c4 + 1]) * is_[c4 + 1];
      ks_[lr + rr][c4 + 2] = expf(kv.z - mx[c4 + 2]) * is_[c4 + 2];
      ks_[lr + rr][c4 + 3] = expf(kv.w - mx[c4 + 3]) * is_[c4 + 3];
      vs_[lr + rr][c4 + 0] = vv.x;
      vs_[lr + rr][c4 + 1] = vv.y;
      vs_[lr + rr][c4 + 2] = vv.z;
      vs_[lr + rr][c4 + 3] = vv.w;
    }
    __syncthreads();
#pragma unroll
    for (int nn = 0; nn < 32; ++nn) {
      float av[4], bv2[4];
#pragma unroll
      for (int i = 0; i < 4; ++i) av[i] = ks_[nn][ty * 4 + i];
#pragma unroll
      for (int j = 0; j < 4; ++j) bv2[j] = vs_[nn][tx * 4 + j];
#pragma unroll
      for (int i = 0; i < 4; ++i)
#pragma unroll
        for (int j = 0; j < 4; ++j) acc[i][j] += av[i] * bv2[j];
    }
  }
  float* ap = attn + (size_t)(b * H_ + h) * 4096;
#pragma unroll
  for (int i = 0; i < 4; ++i)
#pragma unroll
    for (int j = 0; j < 4; ++j)
      atomicAdd(&ap[(ty * 4 + i) * 64 + tx * 4 + j], acc[i][j]);
}

// ---------------- emb modulation: eo = silu(emb) @ We + be ----------------
__global__ void __launch_bounds__(256) embmod(const float* __restrict__ emb,
                                              const float* __restrict__ We,
                                              const float* __restrict__ be,
                                              float* __restrict__ eo) {
  int b = blockIdx.x, tid = threadIdx.x;
  __shared__ float se[TE_];
  for (int i = tid; i < TE_; i += 256) {
    float e = emb[b * TE_ + i];
    se[i] = e / (1.f + expf(-e));
  }
  __syncthreads();
  int j0 = tid * 4;
  float a0 = 0, a1 = 0, a2 = 0, a3 = 0;
  for (int i = 0; i < TE_; ++i) {
    float s = se[i];
    float4 wv = *(const float4*)&We[(size_t)i * 1024 + j0];
    a0 += s * wv.x;
    a1 += s * wv.y;
    a2 += s * wv.z;
    a3 += s * wv.w;
  }
  eo[b * 1024 + j0 + 0] = a0 + be[j0 + 0];
  eo[b * 1024 + j0 + 1] = a1 + be[j0 + 1];
  eo[b * 1024 + j0 + 2] = a2 + be[j0 + 2];
  eo[b * 1024 + j0 + 3] = a3 + be[j0 + 3];
}

// ---------------- y[b,t,h,:] = q[b,t,h,:] @ attn[b,h]  (q is bf16) ----------------
__global__ void __launch_bounds__(256) yein(const unsigned short* __restrict__ q,
                                            const float* __restrict__ attn,
                                            float* __restrict__ y) {
  int t0 = blockIdx.x * 32, h = blockIdx.y, b = blockIdx.z;
  int tid = threadIdx.x;
  __shared__ float at[64][68];
  __shared__ float qs[32][68];
  const float* ap = attn + (size_t)(b * H_ + h) * 4096;
  for (int i = tid; i < 4096; i += 256) at[i >> 6][i & 63] = ap[i];
  const unsigned short* qp = q + ((size_t)b * T_ + t0) * D_ + h * 64;
  for (int i = tid; i < 2048; i += 256)
    qs[i >> 6][i & 63] = bf2f(qp[(size_t)(i >> 6) * D_ + (i & 63)]);
  __syncthreads();
  int r = tid >> 3, c0 = (tid & 7) * 8;
  float acc[8] = {};
#pragma unroll
  for (int d = 0; d < 64; ++d) {
    float qv = qs[r][d];
#pragma unroll
    for (int j = 0; j < 8; ++j) acc[j] += qv * at[d][c0 + j];
  }
  float* yp = y + ((size_t)b * T_ + t0 + r) * D_ + h * 64 + c0;
#pragma unroll
  for (int j = 0; j < 8; ++j) yp[j] = acc[j];
}

// ---------------- LN(y) * (1+scale) + shift, then silu -> bf16 ----------------
__global__ void __launch_bounds__(256) modln(const float* __restrict__ y,
                                             const float* __restrict__ sg,
                                             const float* __restrict__ sb,
                                             const float* __restrict__ eo,
                                             unsigned short* __restrict__ hs) {
  __shared__ float ws[4];
  size_t row = blockIdx.x;
  int b = (int)(row >> 11);
  const float* rp = y + row * D_;
  float v[2];
  float s = 0.f;
#pragma unroll
  for (int e = 0; e < 2; ++e) {
    v[e] = rp[threadIdx.x + e * 256];
    s += v[e];
  }
  s = blockReduceSum(s, ws);
  float mean = s * (1.0f / D_);
  float q = 0.f;
#pragma unroll
  for (int e = 0; e < 2; ++e) {
    float d = v[e] - mean;
    q += d * d;
  }
  q = blockReduceSum(q, ws);
  float rstd = rsqrtf(q * (1.0f / D_) + 1e-5f);
#pragma unroll
  for (int e = 0; e < 2; ++e) {
    int c = threadIdx.x + e * 256;
    float xm = (v[e] - mean) * rstd * sg[c] + sb[c];
    float sc = eo[b * 1024 + c];
    float sh = eo[b * 1024 + D_ + c];
    float hm = xm * (1.f + sc) + sh;
    hs[row * D_ + c] = f2bf(hm / (1.f + expf(-hm)));
  }
}

extern "C" void kernel_launch(void* const* d_in, const int* in_sizes, int n_in,
                              void* d_out, int out_size, void* d_ws, size_t ws_size,
                              hipStream_t stream) {
  const float* x = (const float*)d_in[0];
  const float* xf = (const float*)d_in[1];
  const float* emb = (const float*)d_in[2];
  const float* norm_g = (const float*)d_in[3];
  const float* norm_b = (const float*)d_in[4];
  const float* tnorm_g = (const float*)d_in[5];
  const float* tnorm_b = (const float*)d_in[6];
  const float* Wq = (const float*)d_in[7];
  const float* bq = (const float*)d_in[8];
  const float* Wk = (const float*)d_in[9];
  const float* bk = (const float*)d_in[10];
  const float* Wv = (const float*)d_in[11];
  const float* bv = (const float*)d_in[12];
  const float* We = (const float*)d_in[13];
  const float* be = (const float*)d_in[14];
  const float* sg = (const float*)d_in[15];
  const float* sb = (const float*)d_in[16];
  const float* Wo = (const float*)d_in[17];
  const float* bo = (const float*)d_in[18];
  float* out = (float*)d_out;

  float* w = (float*)d_ws;
  // layout (floats):
  unsigned short* qbf = (unsigned short*)w;               // 33.5M ushort = 16.78M floats
  float* kbuf = w + 16777216;                             // 33.5M floats (k -> y)
  float* vbuf = w + 16777216 + 33554432;                  // 33.5M floats
  unsigned short* xnbf = (unsigned short*)(w + 83886080); // 33.5M ushort (xn -> hs)
  unsigned short* xfnbf = (unsigned short*)(w + 100663296); // 16.78M ushort
  float* attn = w + 109051904;                            // 1,048,576
  float* kmaxp = attn + 1048576;                          // 16384
  float* ksump = kmaxp + 16384;                           // 16384
  float* embout = ksump + 16384;                          // 32768
  unsigned short* wqt = (unsigned short*)(embout + 32768);  // 512*512
  unsigned short* wkt = wqt + 262144;                       // 512*256
  unsigned short* wvt = wkt + 131072;                       // 512*256
  unsigned short* wot = wvt + 131072;                       // 512*512
  // kstats partials: reuse the xnbf float region (dead between step 2 and step 11)
  float* pmaxp = w + 83886080;                            // 32*KCH*512 floats
  float* psump = pmaxp + (size_t)B_ * KCH * D_;           // 32*KCH*512 floats
  // total ~110.6M floats = 442 MiB

  // 0. weight transpose-casts (tiny)
  transcast<<<dim3(16, 16), 256, 0, stream>>>(Wq, wqt, 512, 512);
  transcast<<<dim3(8, 16), 256, 0, stream>>>(Wk, wkt, 256, 512);
  transcast<<<dim3(8, 16), 256, 0, stream>>>(Wv, wvt, 256, 512);
  transcast<<<dim3(16, 16), 256, 0, stream>>>(Wo, wot, 512, 512);
  // 1. xn = LN(x) -> bf16
  ln_rows<512><<<MROWS, 256, 0, stream>>>(x, norm_g, norm_b, xnbf);
  // 2. q = xn @ Wq + bq -> bf16
  gemm_mfma<512, false, true><<<dim3(4, 512), 256, 0, stream>>>(xnbf, wqt, bq, nullptr, qbf);
  // 3. xfn = LN(xf) -> bf16
  ln_rows<256><<<MROWS, 256, 0, stream>>>(xf, tnorm_g, tnorm_b, xfnbf);
  // 4. k = xfn @ Wk + bk -> fp32
  gemm_mfma<256, false, false><<<dim3(4, 512), 256, 0, stream>>>(xfnbf, wkt, bk, nullptr, kbuf);
  // 5. v = xfn @ Wv + bv -> fp32
  gemm_mfma<256, false, false><<<dim3(4, 512), 256, 0, stream>>>(xfnbf, wvt, bv, nullptr, vbuf);
  // 6. k softmax stats: chunked partials (16 n-chunks) + combine
  kstats_part<<<dim3(32, 8, KCH), 256, 0, stream>>>(kbuf, pmaxp, psump);
  kstats_comb<<<dim3(32, 2), 256, 0, stream>>>(pmaxp, psump, kmaxp, ksump);
  // 7. attn = softmax(k)^T @ v
  hipMemsetAsync(attn, 0, (size_t)1048576 * 4, stream);
  attn_kernel<<<dim3(32, 8, 8), 256, 0, stream>>>(kbuf, vbuf, kmaxp, ksump, attn);
  // 8. emb modulation
  embmod<<<32, 256, 0, stream>>>(emb, We, be, embout);
  // 9. q softmax (in place, bf16)
  qsoftmax<<<131072, 256, 0, stream>>>(qbf);
  // 10. y = q @ attn -> kbuf (k dead)
  yein<<<dim3(64, 8, 32), 256, 0, stream>>>(qbf, attn, kbuf);
  // 11. hs = silu(LN(y)*(1+scale)+shift) -> bf16 into xnbf (xn dead)
  modln<<<MROWS, 256, 0, stream>>>(kbuf, sg, sb, embout, xnbf);
  // 12. out = hs @ Wo + bo + x
  gemm_mfma<512, true, false><<<dim3(4, 512), 256, 0, stream>>>(xnbf, wot, bo, x, out);
}

// Round 2
// 945.998 us; speedup vs baseline: 1.4344x; 1.1378x over previous
//
#include <hip/hip_runtime.h>
#include <math.h>

#define B_ 32
#define T_ 2048
#define N_ 2048
#define D_ 512
#define L_ 256
#define TE_ 1024
#define H_ 8
#define MROWS 65536  // B*T = B*N
#define KCH 16       // n-chunks for kstats partial reduction
#define NC_ 8        // n-chunks for attn partial accumulation

typedef __attribute__((ext_vector_type(8))) short short8;
typedef __attribute__((ext_vector_type(4))) float f32x4;

__device__ __forceinline__ unsigned short f2bf(float f) {
  unsigned u = __float_as_uint(f);
  unsigned r = (u + 0x7FFF + ((u >> 16) & 1)) >> 16;  // RNE
  return (unsigned short)r;
}
__device__ __forceinline__ float bf2f(unsigned short u) {
  return __uint_as_float(((unsigned)u) << 16);
}
__device__ __forceinline__ void gload_lds16(const void* g, void* l) {
  __builtin_amdgcn_global_load_lds(
      (const __attribute__((address_space(1))) void*)g,
      (__attribute__((address_space(3))) void*)l, 16, 0, 0);
}

// ---------------- block reduce (256 threads) ----------------
__device__ __forceinline__ float blockReduceSum(float v, float* ws) {
#pragma unroll
  for (int m = 32; m >= 1; m >>= 1) v += __shfl_xor(v, m, 64);
  int wid = threadIdx.x >> 6;
  int lane = threadIdx.x & 63;
  __syncthreads();
  if (lane == 0) ws[wid] = v;
  __syncthreads();
  return ws[0] + ws[1] + ws[2] + ws[3];
}

// ---------------- row LayerNorm -> bf16 ----------------
template <int COLS>
__global__ void __launch_bounds__(256) ln_rows(const float* __restrict__ in,
                                               const float* __restrict__ g,
                                               const float* __restrict__ bb,
                                               unsigned short* __restrict__ out) {
  constexpr int E = COLS / 256;
  __shared__ float ws[4];
  size_t row = blockIdx.x;
  const float* rp = in + row * COLS;
  float v[E];
  float s = 0.f;
#pragma unroll
  for (int e = 0; e < E; ++e) {
    v[e] = rp[threadIdx.x + e * 256];
    s += v[e];
  }
  s = blockReduceSum(s, ws);
  float mean = s * (1.0f / COLS);
  float q = 0.f;
#pragma unroll
  for (int e = 0; e < E; ++e) {
    float d = v[e] - mean;
    q += d * d;
  }
  q = blockReduceSum(q, ws);
  float rstd = rsqrtf(q * (1.0f / COLS) + 1e-5f);
  unsigned short* op = out + row * COLS;
#pragma unroll
  for (int e = 0; e < E; ++e) {
    int c = threadIdx.x + e * 256;
    op[c] = f2bf((v[e] - mean) * rstd * g[c] + bb[c]);
  }
}

// ---------------- weight transpose + cast: Wt[n][k] = bf16(W[k][n]) ----------------
__global__ void __launch_bounds__(256) transcast(const float* __restrict__ W,
                                                 unsigned short* __restrict__ Wt,
                                                 int K, int Ncols) {
  __shared__ float t[32][33];
  int k0 = blockIdx.x * 32, n0 = blockIdx.y * 32;
  int tx = threadIdx.x & 31, ty = threadIdx.x >> 5;  // 32 x 8
#pragma unroll
  for (int i = 0; i < 32; i += 8)
    t[ty + i][tx] = W[(size_t)(k0 + ty + i) * Ncols + n0 + tx];
  __syncthreads();
#pragma unroll
  for (int i = 0; i < 32; i += 8)
    Wt[(size_t)(n0 + ty + i) * K + k0 + tx] = f2bf(t[tx][ty + i]);
}

// ---------------- bf16 MFMA GEMM: C[M,512] = A[M,KT] @ Wt[512,KT]^T + bias (+add) ----------------
// 128x128 tile, 4 waves in 2x2, each wave 64x64 as 4x4 of 16x16x32 MFMA.
template <int KT, bool ADD, bool OUTBF>
__global__ void __launch_bounds__(256) gemm_mfma(const unsigned short* __restrict__ A,
                                                 const unsigned short* __restrict__ Wt,
                                                 const float* __restrict__ bias,
                                                 const float* __restrict__ add,
                                                 void* __restrict__ Cv) {
  __shared__ __align__(16) unsigned short sA[128 * 32];
  __shared__ __align__(16) unsigned short sB[128 * 32];
  int tid = threadIdx.x;
  int w = tid >> 6, lane = tid & 63;
  int quad = lane >> 4, r16 = lane & 15;
  int wr = w >> 1, wc = w & 1;
  size_t m0 = (size_t)blockIdx.y * 128;
  int n0 = blockIdx.x * 128;
  int srow = lane >> 2;        // 0..15
  int scol = (lane & 3) * 8;   // ushort offset within 32-wide K slice
  f32x4 acc[4][4] = {};

  for (int k0 = 0; k0 < KT; k0 += 32) {
    __syncthreads();  // previous compute must finish before LDS overwrite
#pragma unroll
    for (int i = 0; i < 2; ++i) {
      int seg = w * 2 + i;  // 0..7, 16 rows each
      gload_lds16(&A[(m0 + seg * 16 + srow) * KT + k0 + scol], &sA[seg * 512]);
    }
#pragma unroll
    for (int i = 0; i < 2; ++i) {
      int seg = w * 2 + i;
      gload_lds16(&Wt[(size_t)(n0 + seg * 16 + srow) * KT + k0 + scol], &sB[seg * 512]);
    }
    __syncthreads();  // compiler drains vmcnt here (global_load_lds done)
    short8 af[4], bfr[4];
#pragma unroll
    for (int mi = 0; mi < 4; ++mi)
      af[mi] = *(const short8*)&sA[(wr * 64 + mi * 16 + r16) * 32 + quad * 8];
#pragma unroll
    for (int ni = 0; ni < 4; ++ni)
      bfr[ni] = *(const short8*)&sB[(wc * 64 + ni * 16 + r16) * 32 + quad * 8];
#pragma unroll
    for (int mi = 0; mi < 4; ++mi)
#pragma unroll
      for (int ni = 0; ni < 4; ++ni)
        acc[mi][ni] = __builtin_amdgcn_mfma_f32_16x16x32_bf16(af[mi], bfr[ni], acc[mi][ni], 0, 0, 0);
  }

  float* Cf = (float*)Cv;
  unsigned short* Cb = (unsigned short*)Cv;
#pragma unroll
  for (int mi = 0; mi < 4; ++mi)
#pragma unroll
    for (int r = 0; r < 4; ++r) {
      size_t grow = m0 + wr * 64 + mi * 16 + quad * 4 + r;
#pragma unroll
      for (int ni = 0; ni < 4; ++ni) {
        int gcol = n0 + wc * 64 + ni * 16 + r16;
        float val = acc[mi][ni][r] + bias[gcol];
        if constexpr (ADD) val += add[grow * 512 + gcol];
        if constexpr (OUTBF)
          Cb[grow * 512 + gcol] = f2bf(val);
        else
          Cf[grow * 512 + gcol] = val;
      }
    }
}

// ---------------- k softmax partial stats over an n-chunk (per b, channel) ----------------
__global__ void __launch_bounds__(256) kstats_part(const float* __restrict__ k,
                                                   float* __restrict__ pmax,
                                                   float* __restrict__ psum) {
  int b = blockIdx.x, cg = blockIdx.y, ch = blockIdx.z;
  int tid = threadIdx.x;
  int lane = tid & 63, slice = tid >> 6;  // 4 slices over rows
  int c = cg * 64 + lane;
  constexpr int ROWS = N_ / KCH;          // 128
  constexpr int PT = ROWS / 4;            // 32 values per thread
  const float* kp = k + ((size_t)b * N_ + (size_t)ch * ROWS) * D_ + c;
  float v[PT];
#pragma unroll
  for (int i = 0; i < PT; ++i) v[i] = kp[(size_t)(slice + i * 4) * D_];
  float m = v[0];
#pragma unroll
  for (int i = 1; i < PT; ++i) m = fmaxf(m, v[i]);
  float s = 0.f;
#pragma unroll
  for (int i = 0; i < PT; ++i) s += expf(v[i] - m);
  __shared__ float mred[256], sred[256];
  mred[tid] = m;
  sred[tid] = s;
  __syncthreads();
  if (tid < 64) {
    float m0 = mred[tid], m1 = mred[tid + 64], m2 = mred[tid + 128], m3 = mred[tid + 192];
    float mm = fmaxf(fmaxf(m0, m1), fmaxf(m2, m3));
    float ss = sred[tid] * expf(m0 - mm) + sred[tid + 64] * expf(m1 - mm) +
               sred[tid + 128] * expf(m2 - mm) + sred[tid + 192] * expf(m3 - mm);
    pmax[((size_t)b * KCH + ch) * D_ + cg * 64 + tid] = mm;
    psum[((size_t)b * KCH + ch) * D_ + cg * 64 + tid] = ss;
  }
}

// ---------------- combine KCH partial stats -> kmax/ksum ----------------
__global__ void __launch_bounds__(256) kstats_comb(const float* __restrict__ pmax,
                                                   const float* __restrict__ psum,
                                                   float* __restrict__ kmax,
                                                   float* __restrict__ ksum) {
  int b = blockIdx.x;
  int c = blockIdx.y * 256 + threadIdx.x;
  float pm[KCH];
#pragma unroll
  for (int ch = 0; ch < KCH; ++ch) pm[ch] = pmax[((size_t)b * KCH + ch) * D_ + c];
  float m = pm[0];
#pragma unroll
  for (int ch = 1; ch < KCH; ++ch) m = fmaxf(m, pm[ch]);
  float s = 0.f;
#pragma unroll
  for (int ch = 0; ch < KCH; ++ch)
    s += psum[((size_t)b * KCH + ch) * D_ + c] * expf(pm[ch] - m);
  kmax[b * D_ + c] = m;
  ksum[b * D_ + c] = s;
}

// ---------------- attn_part[b,h,nc] = softmax(k)^T @ v over an n-chunk of 256 ----------------
// Plain stores per (b,h,nc) partial buffer: no atomics, no RMW write amplification.
__global__ void __launch_bounds__(256) attn_part_kernel(const float* __restrict__ k,
                                                        const float* __restrict__ v,
                                                        const float* __restrict__ kmax,
                                                        const float* __restrict__ ksum,
                                                        float* __restrict__ part) {
  int b = blockIdx.x, h = blockIdx.y, nc = blockIdx.z;
  int tid = threadIdx.x;
  __shared__ float ks_[32][68];
  __shared__ float vs_[32][68];
  __shared__ float mx[64], is_[64];
  if (tid < 64) {
    mx[tid] = kmax[b * D_ + h * 64 + tid];
    is_[tid] = 1.f / ksum[b * D_ + h * 64 + tid];
  }
  const float* kp = k + ((size_t)b * N_ + nc * 256) * D_ + h * 64;
  const float* vp = v + ((size_t)b * N_ + nc * 256) * D_ + h * 64;
  float acc[4][4] = {};
  int tx = tid & 15, ty = tid >> 4;
  int lr = tid >> 4;
  int c4 = (tid & 15) * 4;
  for (int n0 = 0; n0 < 256; n0 += 32) {
    __syncthreads();
#pragma unroll
    for (int rr = 0; rr < 32; rr += 16) {
      float4 kv = *(const float4*)&kp[(size_t)(n0 + lr + rr) * D_ + c4];
      float4 vv = *(const float4*)&vp[(size_t)(n0 + lr + rr) * D_ + c4];
      ks_[lr + rr][c4 + 0] = expf(kv.x - mx[c4 + 0]) * is_[c4 + 0];
      ks_[lr + rr][c4 + 1] = expf(kv.y - mx[c4 + 1]) * is_[c4 + 1];
      ks_[lr + rr][c4 + 2] = expf(kv.z - mx[c4 + 2]) * is_[c4 + 2];
      ks_[lr + rr][c4 + 3] = expf(kv.w - mx[c4 + 3]) * is_[c4 + 3];
      vs_[lr + rr][c4 + 0] = vv.x;
      vs_[lr + rr][c4 + 1] = vv.y;
      vs_[lr + rr][c4 + 2] = vv.z;
      vs_[lr + rr][c4 + 3] = vv.w;
    }
    __syncthreads();
#pragma unroll
    for (int nn = 0; nn < 32; ++nn) {
      float av[4], bv2[4];
#pragma unroll
      for (int i = 0; i < 4; ++i) av[i] = ks_[nn][ty * 4 + i];
#pragma unroll
      for (int j = 0; j < 4; ++j) bv2[j] = vs_[nn][tx * 4 + j];
#pragma unroll
      for (int i = 0; i < 4; ++i)
#pragma unroll
        for (int j = 0; j < 4; ++j) acc[i][j] += av[i] * bv2[j];
    }
  }
  float* ap = part + ((size_t)(b * H_ + h) * NC_ + nc) * 4096;
#pragma unroll
  for (int i = 0; i < 4; ++i) {
    float4 st = make_float4(acc[i][0], acc[i][1], acc[i][2], acc[i][3]);
    *(float4*)&ap[(ty * 4 + i) * 64 + tx * 4] = st;
  }
}

// ---------------- reduce NC_ partials -> attn ----------------
__global__ void __launch_bounds__(256) attn_reduce(const float* __restrict__ part,
                                                   float* __restrict__ attn) {
  size_t o = ((size_t)blockIdx.x * 256 + threadIdx.x) * 4;  // 1M floats total
  size_t bh = o >> 12;
  size_t e = o & 4095;
  float4 s = make_float4(0.f, 0.f, 0.f, 0.f);
#pragma unroll
  for (int nc = 0; nc < NC_; ++nc) {
    float4 p = *(const float4*)&part[(bh * NC_ + nc) * 4096 + e];
    s.x += p.x;
    s.y += p.y;
    s.z += p.z;
    s.w += p.w;
  }
  *(float4*)&attn[o] = s;
}

// ---------------- emb modulation: eo = silu(emb) @ We + be ----------------
__global__ void __launch_bounds__(256) embmod(const float* __restrict__ emb,
                                              const float* __restrict__ We,
                                              const float* __restrict__ be,
                                              float* __restrict__ eo) {
  int b = blockIdx.x, tid = threadIdx.x;
  __shared__ float se[TE_];
  for (int i = tid; i < TE_; i += 256) {
    float e = emb[b * TE_ + i];
    se[i] = e / (1.f + expf(-e));
  }
  __syncthreads();
  int j0 = tid * 4;
  float a0 = 0, a1 = 0, a2 = 0, a3 = 0;
  for (int i = 0; i < TE_; ++i) {
    float s = se[i];
    float4 wv = *(const float4*)&We[(size_t)i * 1024 + j0];
    a0 += s * wv.x;
    a1 += s * wv.y;
    a2 += s * wv.z;
    a3 += s * wv.w;
  }
  eo[b * 1024 + j0 + 0] = a0 + be[j0 + 0];
  eo[b * 1024 + j0 + 1] = a1 + be[j0 + 1];
  eo[b * 1024 + j0 + 2] = a2 + be[j0 + 2];
  eo[b * 1024 + j0 + 3] = a3 + be[j0 + 3];
}

// ---------------- y[b,t,h,:] = softmax(q[b,t,h,:]) @ attn[b,h]  (q raw bf16) ----------------
// q-softmax fused: the softmax axis (hd=64) is exactly the staged tile width.
__global__ void __launch_bounds__(256) yein(const unsigned short* __restrict__ q,
                                            const float* __restrict__ attn,
                                            float* __restrict__ y) {
  int t0 = blockIdx.x * 32, h = blockIdx.y, b = blockIdx.z;
  int tid = threadIdx.x;
  __shared__ float at[64][68];
  __shared__ float qs[32][68];
  const float* ap = attn + (size_t)(b * H_ + h) * 4096;
  for (int i = tid; i < 4096; i += 256) at[i >> 6][i & 63] = ap[i];
  const unsigned short* qp = q + ((size_t)b * T_ + t0) * D_ + h * 64;
  for (int i = tid; i < 2048; i += 256)
    qs[i >> 6][i & 63] = bf2f(qp[(size_t)(i >> 6) * D_ + (i & 63)]);
  __syncthreads();
  int r = tid >> 3, c0 = (tid & 7) * 8;
  // fused softmax over row r (8 threads per row, same wave: lane bits 0..2)
  float lv[8];
#pragma unroll
  for (int j = 0; j < 8; ++j) lv[j] = qs[r][c0 + j];
  float m = lv[0];
#pragma unroll
  for (int j = 1; j < 8; ++j) m = fmaxf(m, lv[j]);
#pragma unroll
  for (int s = 4; s >= 1; s >>= 1) m = fmaxf(m, __shfl_xor(m, s, 64));
  float ssum = 0.f;
#pragma unroll
  for (int j = 0; j < 8; ++j) {
    lv[j] = expf(lv[j] - m);
    ssum += lv[j];
  }
#pragma unroll
  for (int s = 4; s >= 1; s >>= 1) ssum += __shfl_xor(ssum, s, 64);
  float inv = 1.f / ssum;  // defer division: y = (e @ at) * inv
#pragma unroll
  for (int j = 0; j < 8; ++j) qs[r][c0 + j] = lv[j];
  __syncthreads();
  float acc[8] = {};
#pragma unroll
  for (int d = 0; d < 64; ++d) {
    float qv = qs[r][d];
#pragma unroll
    for (int j = 0; j < 8; ++j) acc[j] += qv * at[d][c0 + j];
  }
  float* yp = y + ((size_t)b * T_ + t0 + r) * D_ + h * 64 + c0;
#pragma unroll
  for (int j = 0; j < 8; ++j) yp[j] = acc[j] * inv;
}

// ---------------- LN(y) * (1+scale) + shift, then silu -> bf16 ----------------
__global__ void __launch_bounds__(256) modln(const float* __restrict__ y,
                                             const float* __restrict__ sg,
                                             const float* __restrict__ sb,
                                             const float* __restrict__ eo,
                                             unsigned short* __restrict__ hs) {
  __shared__ float ws[4];
  size_t row = blockIdx.x;
  int b = (int)(row >> 11);
  const float* rp = y + row * D_;
  float v[2];
  float s = 0.f;
#pragma unroll
  for (int e = 0; e < 2; ++e) {
    v[e] = rp[threadIdx.x + e * 256];
    s += v[e];
  }
  s = blockReduceSum(s, ws);
  float mean = s * (1.0f / D_);
  float q = 0.f;
#pragma unroll
  for (int e = 0; e < 2; ++e) {
    float d = v[e] - mean;
    q += d * d;
  }
  q = blockReduceSum(q, ws);
  float rstd = rsqrtf(q * (1.0f / D_) + 1e-5f);
#pragma unroll
  for (int e = 0; e < 2; ++e) {
    int c = threadIdx.x + e * 256;
    float xm = (v[e] - mean) * rstd * sg[c] + sb[c];
    float sc = eo[b * 1024 + c];
    float sh = eo[b * 1024 + D_ + c];
    float hm = xm * (1.f + sc) + sh;
    hs[row * D_ + c] = f2bf(hm / (1.f + expf(-hm)));
  }
}

extern "C" void kernel_launch(void* const* d_in, const int* in_sizes, int n_in,
                              void* d_out, int out_size, void* d_ws, size_t ws_size,
                              hipStream_t stream) {
  const float* x = (const float*)d_in[0];
  const float* xf = (const float*)d_in[1];
  const float* emb = (const float*)d_in[2];
  const float* norm_g = (const float*)d_in[3];
  const float* norm_b = (const float*)d_in[4];
  const float* tnorm_g = (const float*)d_in[5];
  const float* tnorm_b = (const float*)d_in[6];
  const float* Wq = (const float*)d_in[7];
  const float* bq = (const float*)d_in[8];
  const float* Wk = (const float*)d_in[9];
  const float* bk = (const float*)d_in[10];
  const float* Wv = (const float*)d_in[11];
  const float* bv = (const float*)d_in[12];
  const float* We = (const float*)d_in[13];
  const float* be = (const float*)d_in[14];
  const float* sg = (const float*)d_in[15];
  const float* sb = (const float*)d_in[16];
  const float* Wo = (const float*)d_in[17];
  const float* bo = (const float*)d_in[18];
  float* out = (float*)d_out;

  float* w = (float*)d_ws;
  // layout (floats):
  unsigned short* qbf = (unsigned short*)w;               // 33.5M ushort = 16.78M floats
  float* kbuf = w + 16777216;                             // 33.5M floats (k -> y)
  float* vbuf = w + 16777216 + 33554432;                  // 33.5M floats
  unsigned short* xnbf = (unsigned short*)(w + 83886080); // 33.5M ushort (xn -> hs)
  unsigned short* xfnbf = (unsigned short*)(w + 100663296); // 16.78M ushort
  float* attn = w + 109051904;                            // 1,048,576
  float* kmaxp = attn + 1048576;                          // 16384
  float* ksump = kmaxp + 16384;                           // 16384
  float* embout = ksump + 16384;                          // 32768
  unsigned short* wqt = (unsigned short*)(embout + 32768);  // 512*512
  unsigned short* wkt = wqt + 262144;                       // 512*256
  unsigned short* wvt = wkt + 131072;                       // 512*256
  unsigned short* wot = wvt + 131072;                       // 512*512
  // kstats partials: reuse the xnbf float region (dead between step 2 and step 11)
  float* pmaxp = w + 83886080;                            // 32*KCH*512 floats
  float* psump = pmaxp + (size_t)B_ * KCH * D_;           // 32*KCH*512 floats
  // attn partials: reuse the xfnbf region (dead after step 5) — 32*8*8*4096 = 8,388,608 floats exact fit
  float* attnpart = w + 100663296;

  // 0. weight transpose-casts (tiny)
  transcast<<<dim3(16, 16), 256, 0, stream>>>(Wq, wqt, 512, 512);
  transcast<<<dim3(8, 16), 256, 0, stream>>>(Wk, wkt, 256, 512);
  transcast<<<dim3(8, 16), 256, 0, stream>>>(Wv, wvt, 256, 512);
  transcast<<<dim3(16, 16), 256, 0, stream>>>(Wo, wot, 512, 512);
  // 1. xn = LN(x) -> bf16
  ln_rows<512><<<MROWS, 256, 0, stream>>>(x, norm_g, norm_b, xnbf);
  // 2. q = xn @ Wq + bq -> bf16 (raw; softmax fused into yein)
  gemm_mfma<512, false, true><<<dim3(4, 512), 256, 0, stream>>>(xnbf, wqt, bq, nullptr, qbf);
  // 3. xfn = LN(xf) -> bf16
  ln_rows<256><<<MROWS, 256, 0, stream>>>(xf, tnorm_g, tnorm_b, xfnbf);
  // 4. k = xfn @ Wk + bk -> fp32
  gemm_mfma<256, false, false><<<dim3(4, 512), 256, 0, stream>>>(xfnbf, wkt, bk, nullptr, kbuf);
  // 5. v = xfn @ Wv + bv -> fp32
  gemm_mfma<256, false, false><<<dim3(4, 512), 256, 0, stream>>>(xfnbf, wvt, bv, nullptr, vbuf);
  // 6. k softmax stats: chunked partials (16 n-chunks) + combine
  kstats_part<<<dim3(32, 8, KCH), 256, 0, stream>>>(kbuf, pmaxp, psump);
  kstats_comb<<<dim3(32, 2), 256, 0, stream>>>(pmaxp, psump, kmaxp, ksump);
  // 7. attn partials (no atomics) + reduce
  attn_part_kernel<<<dim3(32, 8, NC_), 256, 0, stream>>>(kbuf, vbuf, kmaxp, ksump, attnpart);
  attn_reduce<<<1024, 256, 0, stream>>>(attnpart, attn);
  // 8. emb modulation
  embmod<<<32, 256, 0, stream>>>(emb, We, be, embout);
  // 9. y = softmax(q) @ attn -> kbuf (k dead); q-softmax fused
  yein<<<dim3(64, 8, 32), 256, 0, stream>>>(qbf, attn, kbuf);
  // 10. hs = silu(LN(y)*(1+scale)+shift) -> bf16 into xnbf (xn dead)
  modln<<<MROWS, 256, 0, stream>>>(kbuf, sg, sb, embout, xnbf);
  // 11. out = hs @ Wo + bo + x
  gemm_mfma<512, true, false><<<dim3(4, 512), 256, 0, stream>>>(xnbf, wot, bo, x, out);
}

// Round 3
// 941.052 us; speedup vs baseline: 1.4419x; 1.0053x over previous
//
#include <hip/hip_runtime.h>
#include <math.h>

#define B_ 32
#define T_ 2048
#define N_ 2048
#define D_ 512
#define L_ 256
#define TE_ 1024
#define H_ 8
#define MROWS 65536  // B*T = B*N
#define KCH 16       // n-chunks for kstats partial reduction
#define NC_ 8        // n-chunks for attn partial accumulation

typedef __attribute__((ext_vector_type(8))) short short8;
typedef __attribute__((ext_vector_type(4))) float f32x4;

__device__ __forceinline__ unsigned short f2bf(float f) {
  unsigned u = __float_as_uint(f);
  unsigned r = (u + 0x7FFF + ((u >> 16) & 1)) >> 16;  // RNE
  return (unsigned short)r;
}
__device__ __forceinline__ float bf2f(unsigned short u) {
  return __uint_as_float(((unsigned)u) << 16);
}
__device__ __forceinline__ void gload_lds16(const void* g, void* l) {
  __builtin_amdgcn_global_load_lds(
      (const __attribute__((address_space(1))) void*)g,
      (__attribute__((address_space(3))) void*)l, 16, 0, 0);
}

// ---------------- block reduce (256 threads) ----------------
__device__ __forceinline__ float blockReduceSum(float v, float* ws) {
#pragma unroll
  for (int m = 32; m >= 1; m >>= 1) v += __shfl_xor(v, m, 64);
  int wid = threadIdx.x >> 6;
  int lane = threadIdx.x & 63;
  __syncthreads();
  if (lane == 0) ws[wid] = v;
  __syncthreads();
  return ws[0] + ws[1] + ws[2] + ws[3];
}

// ---------------- row LayerNorm -> bf16 ----------------
template <int COLS>
__global__ void __launch_bounds__(256) ln_rows(const float* __restrict__ in,
                                               const float* __restrict__ g,
                                               const float* __restrict__ bb,
                                               unsigned short* __restrict__ out) {
  constexpr int E = COLS / 256;
  __shared__ float ws[4];
  size_t row = blockIdx.x;
  const float* rp = in + row * COLS;
  float v[E];
  float s = 0.f;
#pragma unroll
  for (int e = 0; e < E; ++e) {
    v[e] = rp[threadIdx.x + e * 256];
    s += v[e];
  }
  s = blockReduceSum(s, ws);
  float mean = s * (1.0f / COLS);
  float q = 0.f;
#pragma unroll
  for (int e = 0; e < E; ++e) {
    float d = v[e] - mean;
    q += d * d;
  }
  q = blockReduceSum(q, ws);
  float rstd = rsqrtf(q * (1.0f / COLS) + 1e-5f);
  unsigned short* op = out + row * COLS;
#pragma unroll
  for (int e = 0; e < E; ++e) {
    int c = threadIdx.x + e * 256;
    op[c] = f2bf((v[e] - mean) * rstd * g[c] + bb[c]);
  }
}

// ---------------- weight transpose + cast: Wt[n][k] = bf16(W[k][n]) ----------------
__global__ void __launch_bounds__(256) transcast(const float* __restrict__ W,
                                                 unsigned short* __restrict__ Wt,
                                                 int K, int Ncols) {
  __shared__ float t[32][33];
  int k0 = blockIdx.x * 32, n0 = blockIdx.y * 32;
  int tx = threadIdx.x & 31, ty = threadIdx.x >> 5;  // 32 x 8
#pragma unroll
  for (int i = 0; i < 32; i += 8)
    t[ty + i][tx] = W[(size_t)(k0 + ty + i) * Ncols + n0 + tx];
  __syncthreads();
#pragma unroll
  for (int i = 0; i < 32; i += 8)
    Wt[(size_t)(n0 + ty + i) * K + k0 + tx] = f2bf(t[tx][ty + i]);
}

// ---------------- bf16 MFMA GEMM: C[M,512] = A[M,KT] @ Wt[512,KT]^T + bias (+add) ----------------
// 128x128 tile, 4 waves in 2x2, each wave 64x64 as 4x4 of 16x16x32 MFMA.
// QSM: apply softmax over each 64-col group (head) on the fp32 acc before bf16 store.
template <int KT, bool ADD, bool OUTBF, bool QSM>
__global__ void __launch_bounds__(256) gemm_mfma(const unsigned short* __restrict__ A,
                                                 const unsigned short* __restrict__ Wt,
                                                 const float* __restrict__ bias,
                                                 const float* __restrict__ add,
                                                 void* __restrict__ Cv) {
  __shared__ __align__(16) unsigned short sA[128 * 32];
  __shared__ __align__(16) unsigned short sB[128 * 32];
  int tid = threadIdx.x;
  int w = tid >> 6, lane = tid & 63;
  int quad = lane >> 4, r16 = lane & 15;
  int wr = w >> 1, wc = w & 1;
  size_t m0 = (size_t)blockIdx.y * 128;
  int n0 = blockIdx.x * 128;
  int srow = lane >> 2;        // 0..15
  int scol = (lane & 3) * 8;   // ushort offset within 32-wide K slice
  f32x4 acc[4][4] = {};

  for (int k0 = 0; k0 < KT; k0 += 32) {
    __syncthreads();  // previous compute must finish before LDS overwrite
#pragma unroll
    for (int i = 0; i < 2; ++i) {
      int seg = w * 2 + i;  // 0..7, 16 rows each
      gload_lds16(&A[(m0 + seg * 16 + srow) * KT + k0 + scol], &sA[seg * 512]);
    }
#pragma unroll
    for (int i = 0; i < 2; ++i) {
      int seg = w * 2 + i;
      gload_lds16(&Wt[(size_t)(n0 + seg * 16 + srow) * KT + k0 + scol], &sB[seg * 512]);
    }
    __syncthreads();  // compiler drains vmcnt here (global_load_lds done)
    short8 af[4], bfr[4];
#pragma unroll
    for (int mi = 0; mi < 4; ++mi)
      af[mi] = *(const short8*)&sA[(wr * 64 + mi * 16 + r16) * 32 + quad * 8];
#pragma unroll
    for (int ni = 0; ni < 4; ++ni)
      bfr[ni] = *(const short8*)&sB[(wc * 64 + ni * 16 + r16) * 32 + quad * 8];
#pragma unroll
    for (int mi = 0; mi < 4; ++mi)
#pragma unroll
      for (int ni = 0; ni < 4; ++ni)
        acc[mi][ni] = __builtin_amdgcn_mfma_f32_16x16x32_bf16(af[mi], bfr[ni], acc[mi][ni], 0, 0, 0);
  }

  float* Cf = (float*)Cv;
  unsigned short* Cb = (unsigned short*)Cv;
#pragma unroll
  for (int mi = 0; mi < 4; ++mi)
#pragma unroll
    for (int r = 0; r < 4; ++r) {
      size_t grow = m0 + wr * 64 + mi * 16 + quad * 4 + r;
      if constexpr (QSM) {
        // wave's 64 cols = one head; row's 64 vals live in 16 lanes x 4 regs.
        float v4[4];
        float mx = -1e30f;
#pragma unroll
        for (int ni = 0; ni < 4; ++ni) {
          v4[ni] = acc[mi][ni][r] + bias[n0 + wc * 64 + ni * 16 + r16];
          mx = fmaxf(mx, v4[ni]);
        }
#pragma unroll
        for (int s = 8; s >= 1; s >>= 1) mx = fmaxf(mx, __shfl_xor(mx, s, 64));
        float ssum = 0.f;
#pragma unroll
        for (int ni = 0; ni < 4; ++ni) {
          v4[ni] = expf(v4[ni] - mx);
          ssum += v4[ni];
        }
#pragma unroll
        for (int s = 8; s >= 1; s >>= 1) ssum += __shfl_xor(ssum, s, 64);
        float inv = 1.f / ssum;
#pragma unroll
        for (int ni = 0; ni < 4; ++ni) {
          int gcol = n0 + wc * 64 + ni * 16 + r16;
          Cb[grow * 512 + gcol] = f2bf(v4[ni] * inv);
        }
      } else {
#pragma unroll
        for (int ni = 0; ni < 4; ++ni) {
          int gcol = n0 + wc * 64 + ni * 16 + r16;
          float val = acc[mi][ni][r] + bias[gcol];
          if constexpr (ADD) val += add[grow * 512 + gcol];
          if constexpr (OUTBF)
            Cb[grow * 512 + gcol] = f2bf(val);
          else
            Cf[grow * 512 + gcol] = val;
        }
      }
    }
}

// ---------------- k softmax partial stats over an n-chunk (per b, channel) ----------------
__global__ void __launch_bounds__(256) kstats_part(const float* __restrict__ k,
                                                   float* __restrict__ pmax,
                                                   float* __restrict__ psum) {
  int b = blockIdx.x, cg = blockIdx.y, ch = blockIdx.z;
  int tid = threadIdx.x;
  int lane = tid & 63, slice = tid >> 6;  // 4 slices over rows
  int c = cg * 64 + lane;
  constexpr int ROWS = N_ / KCH;          // 128
  constexpr int PT = ROWS / 4;            // 32 values per thread
  const float* kp = k + ((size_t)b * N_ + (size_t)ch * ROWS) * D_ + c;
  float v[PT];
#pragma unroll
  for (int i = 0; i < PT; ++i) v[i] = kp[(size_t)(slice + i * 4) * D_];
  float m = v[0];
#pragma unroll
  for (int i = 1; i < PT; ++i) m = fmaxf(m, v[i]);
  float s = 0.f;
#pragma unroll
  for (int i = 0; i < PT; ++i) s += expf(v[i] - m);
  __shared__ float mred[256], sred[256];
  mred[tid] = m;
  sred[tid] = s;
  __syncthreads();
  if (tid < 64) {
    float m0 = mred[tid], m1 = mred[tid + 64], m2 = mred[tid + 128], m3 = mred[tid + 192];
    float mm = fmaxf(fmaxf(m0, m1), fmaxf(m2, m3));
    float ss = sred[tid] * expf(m0 - mm) + sred[tid + 64] * expf(m1 - mm) +
               sred[tid + 128] * expf(m2 - mm) + sred[tid + 192] * expf(m3 - mm);
    pmax[((size_t)b * KCH + ch) * D_ + cg * 64 + tid] = mm;
    psum[((size_t)b * KCH + ch) * D_ + cg * 64 + tid] = ss;
  }
}

// ---------------- combine KCH partial stats -> kmax/ksum ----------------
__global__ void __launch_bounds__(256) kstats_comb(const float* __restrict__ pmax,
                                                   const float* __restrict__ psum,
                                                   float* __restrict__ kmax,
                                                   float* __restrict__ ksum) {
  int b = blockIdx.x;
  int c = blockIdx.y * 256 + threadIdx.x;
  float pm[KCH];
#pragma unroll
  for (int ch = 0; ch < KCH; ++ch) pm[ch] = pmax[((size_t)b * KCH + ch) * D_ + c];
  float m = pm[0];
#pragma unroll
  for (int ch = 1; ch < KCH; ++ch) m = fmaxf(m, pm[ch]);
  float s = 0.f;
#pragma unroll
  for (int ch = 0; ch < KCH; ++ch)
    s += psum[((size_t)b * KCH + ch) * D_ + c] * expf(pm[ch] - m);
  kmax[b * D_ + c] = m;
  ksum[b * D_ + c] = s;
}

// ---------------- attn_part[b,h,nc] = softmax(k)^T @ v over an n-chunk of 256 ----------------
__global__ void __launch_bounds__(256) attn_part_kernel(const float* __restrict__ k,
                                                        const float* __restrict__ v,
                                                        const float* __restrict__ kmax,
                                                        const float* __restrict__ ksum,
                                                        float* __restrict__ part) {
  int b = blockIdx.x, h = blockIdx.y, nc = blockIdx.z;
  int tid = threadIdx.x;
  __shared__ float ks_[32][68];
  __shared__ float vs_[32][68];
  __shared__ float mx[64], is_[64];
  if (tid < 64) {
    mx[tid] = kmax[b * D_ + h * 64 + tid];
    is_[tid] = 1.f / ksum[b * D_ + h * 64 + tid];
  }
  const float* kp = k + ((size_t)b * N_ + nc * 256) * D_ + h * 64;
  const float* vp = v + ((size_t)b * N_ + nc * 256) * D_ + h * 64;
  float acc[4][4] = {};
  int tx = tid & 15, ty = tid >> 4;
  int lr = tid >> 4;
  int c4 = (tid & 15) * 4;
  for (int n0 = 0; n0 < 256; n0 += 32) {
    __syncthreads();
#pragma unroll
    for (int rr = 0; rr < 32; rr += 16) {
      float4 kv = *(const float4*)&kp[(size_t)(n0 + lr + rr) * D_ + c4];
      float4 vv = *(const float4*)&vp[(size_t)(n0 + lr + rr) * D_ + c4];
      ks_[lr + rr][c4 + 0] = expf(kv.x - mx[c4 + 0]) * is_[c4 + 0];
      ks_[lr + rr][c4 + 1] = expf(kv.y - mx[c4 + 1]) * is_[c4 + 1];
      ks_[lr + rr][c4 + 2] = expf(kv.z - mx[c4 + 2]) * is_[c4 + 2];
      ks_[lr + rr][c4 + 3] = expf(kv.w - mx[c4 + 3]) * is_[c4 + 3];
      vs_[lr + rr][c4 + 0] = vv.x;
      vs_[lr + rr][c4 + 1] = vv.y;
      vs_[lr + rr][c4 + 2] = vv.z;
      vs_[lr + rr][c4 + 3] = vv.w;
    }
    __syncthreads();
#pragma unroll
    for (int nn = 0; nn < 32; ++nn) {
      float av[4], bv2[4];
#pragma unroll
      for (int i = 0; i < 4; ++i) av[i] = ks_[nn][ty * 4 + i];
#pragma unroll
      for (int j = 0; j < 4; ++j) bv2[j] = vs_[nn][tx * 4 + j];
#pragma unroll
      for (int i = 0; i < 4; ++i)
#pragma unroll
        for (int j = 0; j < 4; ++j) acc[i][j] += av[i] * bv2[j];
    }
  }
  float* ap = part + ((size_t)(b * H_ + h) * NC_ + nc) * 4096;
#pragma unroll
  for (int i = 0; i < 4; ++i) {
    float4 st = make_float4(acc[i][0], acc[i][1], acc[i][2], acc[i][3]);
    *(float4*)&ap[(ty * 4 + i) * 64 + tx * 4] = st;
  }
}

// ---------------- reduce NC_ partials -> attnT (bf16, transposed: [l][d]) ----------------
__global__ void __launch_bounds__(256) attn_reduce(const float* __restrict__ part,
                                                   unsigned short* __restrict__ attnT) {
  size_t o = ((size_t)blockIdx.x * 256 + threadIdx.x) * 4;  // 1M elements total
  size_t bh = o >> 12;
  size_t e = o & 4095;
  float4 s = make_float4(0.f, 0.f, 0.f, 0.f);
#pragma unroll
  for (int nc = 0; nc < NC_; ++nc) {
    float4 p = *(const float4*)&part[(bh * NC_ + nc) * 4096 + e];
    s.x += p.x;
    s.y += p.y;
    s.z += p.z;
    s.w += p.w;
  }
  // part element e = d*64 + l  (attn[d][l]); emit attnT[l][d] in bf16
  int d = (int)(e >> 6);
  int l = (int)(e & 63);
  unsigned short* ab = attnT + bh * 4096;
  ab[(l + 0) * 64 + d] = f2bf(s.x);
  ab[(l + 1) * 64 + d] = f2bf(s.y);
  ab[(l + 2) * 64 + d] = f2bf(s.z);
  ab[(l + 3) * 64 + d] = f2bf(s.w);
}

// ---------------- emb modulation: eo = silu(emb) @ We + be ----------------
__global__ void __launch_bounds__(256) embmod(const float* __restrict__ emb,
                                              const float* __restrict__ We,
                                              const float* __restrict__ be,
                                              float* __restrict__ eo) {
  int b = blockIdx.x, tid = threadIdx.x;
  __shared__ float se[TE_];
  for (int i = tid; i < TE_; i += 256) {
    float e = emb[b * TE_ + i];
    se[i] = e / (1.f + expf(-e));
  }
  __syncthreads();
  int j0 = tid * 4;
  float a0 = 0, a1 = 0, a2 = 0, a3 = 0;
  for (int i = 0; i < TE_; ++i) {
    float s = se[i];
    float4 wv = *(const float4*)&We[(size_t)i * 1024 + j0];
    a0 += s * wv.x;
    a1 += s * wv.y;
    a2 += s * wv.z;
    a3 += s * wv.w;
  }
  eo[b * 1024 + j0 + 0] = a0 + be[j0 + 0];
  eo[b * 1024 + j0 + 1] = a1 + be[j0 + 1];
  eo[b * 1024 + j0 + 2] = a2 + be[j0 + 2];
  eo[b * 1024 + j0 + 3] = a3 + be[j0 + 3];
}

// ---------------- y = qsm @ attnT^T via MFMA: per block 256 rows x 64 cols (one head) ----
__global__ void __launch_bounds__(256) yein_mfma(const unsigned short* __restrict__ qsm,
                                                 const unsigned short* __restrict__ attnT,
                                                 float* __restrict__ y) {
  int b = blockIdx.z, h = blockIdx.y;
  size_t t0 = (size_t)blockIdx.x * 256;
  int tid = threadIdx.x;
  int w = tid >> 6, lane = tid & 63;
  int quad = lane >> 4, r16 = lane & 15;
  int srow = lane >> 2;
  int scol = (lane & 3) * 8;
  __shared__ __align__(16) unsigned short sA[256 * 32];  // 16 KB
  __shared__ __align__(16) unsigned short sB[64 * 32];   // 4 KB
  const unsigned short* qp = qsm + ((size_t)b * T_ + t0) * D_ + h * 64;
  const unsigned short* bp = attnT + (size_t)(b * H_ + h) * 4096;
  f32x4 acc[4][4] = {};

  for (int k0 = 0; k0 < 64; k0 += 32) {
    __syncthreads();
#pragma unroll
    for (int i = 0; i < 4; ++i) {
      int seg = w * 4 + i;  // 0..15, 16 rows each
      gload_lds16(&qp[(size_t)(seg * 16 + srow) * D_ + k0 + scol], &sA[seg * 512]);
    }
    gload_lds16(&bp[(w * 16 + srow) * 64 + k0 + scol], &sB[w * 512]);
    __syncthreads();
    short8 af[4], bfr[4];
#pragma unroll
    for (int mi = 0; mi < 4; ++mi)
      af[mi] = *(const short8*)&sA[(w * 64 + mi * 16 + r16) * 32 + quad * 8];
#pragma unroll
    for (int ni = 0; ni < 4; ++ni)
      bfr[ni] = *(const short8*)&sB[(ni * 16 + r16) * 32 + quad * 8];
#pragma unroll
    for (int mi = 0; mi < 4; ++mi)
#pragma unroll
      for (int ni = 0; ni < 4; ++ni)
        acc[mi][ni] = __builtin_amdgcn_mfma_f32_16x16x32_bf16(af[mi], bfr[ni], acc[mi][ni], 0, 0, 0);
  }

#pragma unroll
  for (int mi = 0; mi < 4; ++mi)
#pragma unroll
    for (int r = 0; r < 4; ++r) {
      size_t grow = t0 + w * 64 + mi * 16 + quad * 4 + r;
      float* yp = y + ((size_t)b * T_ + grow) * D_ + h * 64;
#pragma unroll
      for (int ni = 0; ni < 4; ++ni) yp[ni * 16 + r16] = acc[mi][ni][r];
    }
}

// ---------------- LN(y) * (1+scale) + shift, then silu -> bf16 ----------------
__global__ void __launch_bounds__(256) modln(const float* __restrict__ y,
                                             const float* __restrict__ sg,
                                             const float* __restrict__ sb,
                                             const float* __restrict__ eo,
                                             unsigned short* __restrict__ hs) {
  __shared__ float ws[4];
  size_t row = blockIdx.x;
  int b = (int)(row >> 11);
  const float* rp = y + row * D_;
  float v[2];
  float s = 0.f;
#pragma unroll
  for (int e = 0; e < 2; ++e) {
    v[e] = rp[threadIdx.x + e * 256];
    s += v[e];
  }
  s = blockReduceSum(s, ws);
  float mean = s * (1.0f / D_);
  float q = 0.f;
#pragma unroll
  for (int e = 0; e < 2; ++e) {
    float d = v[e] - mean;
    q += d * d;
  }
  q = blockReduceSum(q, ws);
  float rstd = rsqrtf(q * (1.0f / D_) + 1e-5f);
#pragma unroll
  for (int e = 0; e < 2; ++e) {
    int c = threadIdx.x + e * 256;
    float xm = (v[e] - mean) * rstd * sg[c] + sb[c];
    float sc = eo[b * 1024 + c];
    float sh = eo[b * 1024 + D_ + c];
    float hm = xm * (1.f + sc) + sh;
    hs[row * D_ + c] = f2bf(hm / (1.f + expf(-hm)));
  }
}

extern "C" void kernel_launch(void* const* d_in, const int* in_sizes, int n_in,
                              void* d_out, int out_size, void* d_ws, size_t ws_size,
                              hipStream_t stream) {
  const float* x = (const float*)d_in[0];
  const float* xf = (const float*)d_in[1];
  const float* emb = (const float*)d_in[2];
  const float* norm_g = (const float*)d_in[3];
  const float* norm_b = (const float*)d_in[4];
  const float* tnorm_g = (const float*)d_in[5];
  const float* tnorm_b = (const float*)d_in[6];
  const float* Wq = (const float*)d_in[7];
  const float* bq = (const float*)d_in[8];
  const float* Wk = (const float*)d_in[9];
  const float* bk = (const float*)d_in[10];
  const float* Wv = (const float*)d_in[11];
  const float* bv = (const float*)d_in[12];
  const float* We = (const float*)d_in[13];
  const float* be = (const float*)d_in[14];
  const float* sg = (const float*)d_in[15];
  const float* sb = (const float*)d_in[16];
  const float* Wo = (const float*)d_in[17];
  const float* bo = (const float*)d_in[18];
  float* out = (float*)d_out;

  float* w = (float*)d_ws;
  // layout (floats):
  unsigned short* qbf = (unsigned short*)w;               // 33.5M ushort = 16.78M floats
  float* kbuf = w + 16777216;                             // 33.5M floats (k -> y)
  float* vbuf = w + 16777216 + 33554432;                  // 33.5M floats
  unsigned short* xnbf = (unsigned short*)(w + 83886080); // 33.5M ushort (xn -> hs)
  unsigned short* xfnbf = (unsigned short*)(w + 100663296); // 16.78M ushort
  unsigned short* attnT = (unsigned short*)(w + 109051904); // 1M ushort (bf16, [l][d])
  float* kmaxp = w + 109051904 + 1048576;                 // 16384
  float* ksump = kmaxp + 16384;                           // 16384
  float* embout = ksump + 16384;                          // 32768
  unsigned short* wqt = (unsigned short*)(embout + 32768);  // 512*512
  unsigned short* wkt = wqt + 262144;                       // 512*256
  unsigned short* wvt = wkt + 131072;                       // 512*256
  unsigned short* wot = wvt + 131072;                       // 512*512
  // kstats partials: reuse the xnbf float region (dead between step 2 and step 11)
  float* pmaxp = w + 83886080;                            // 32*KCH*512 floats
  float* psump = pmaxp + (size_t)B_ * KCH * D_;           // 32*KCH*512 floats
  // attn partials: reuse the xfnbf region (dead after step 5)
  float* attnpart = w + 100663296;

  // 0. weight transpose-casts (tiny)
  transcast<<<dim3(16, 16), 256, 0, stream>>>(Wq, wqt, 512, 512);
  transcast<<<dim3(8, 16), 256, 0, stream>>>(Wk, wkt, 256, 512);
  transcast<<<dim3(8, 16), 256, 0, stream>>>(Wv, wvt, 256, 512);
  transcast<<<dim3(16, 16), 256, 0, stream>>>(Wo, wot, 512, 512);
  // 1. xn = LN(x) -> bf16
  ln_rows<512><<<MROWS, 256, 0, stream>>>(x, norm_g, norm_b, xnbf);
  // 2. qsm = softmax(xn @ Wq + bq) -> bf16 (softmax fused in epilogue, fp32 acc)
  gemm_mfma<512, false, true, true><<<dim3(4, 512), 256, 0, stream>>>(xnbf, wqt, bq, nullptr, qbf);
  // 3. xfn = LN(xf) -> bf16
  ln_rows<256><<<MROWS, 256, 0, stream>>>(xf, tnorm_g, tnorm_b, xfnbf);
  // 4. k = xfn @ Wk + bk -> fp32
  gemm_mfma<256, false, false, false><<<dim3(4, 512), 256, 0, stream>>>(xfnbf, wkt, bk, nullptr, kbuf);
  // 5. v = xfn @ Wv + bv -> fp32
  gemm_mfma<256, false, false, false><<<dim3(4, 512), 256, 0, stream>>>(xfnbf, wvt, bv, nullptr, vbuf);
  // 6. k softmax stats: chunked partials (16 n-chunks) + combine
  kstats_part<<<dim3(32, 8, KCH), 256, 0, stream>>>(kbuf, pmaxp, psump);
  kstats_comb<<<dim3(32, 2), 256, 0, stream>>>(pmaxp, psump, kmaxp, ksump);
  // 7. attn partials (no atomics) + reduce -> attnT bf16
  attn_part_kernel<<<dim3(32, 8, NC_), 256, 0, stream>>>(kbuf, vbuf, kmaxp, ksump, attnpart);
  attn_reduce<<<1024, 256, 0, stream>>>(attnpart, attnT);
  // 8. emb modulation
  embmod<<<32, 256, 0, stream>>>(emb, We, be, embout);
  // 9. y = qsm @ attn -> kbuf (k dead) via MFMA
  yein_mfma<<<dim3(8, 8, 32), 256, 0, stream>>>(qbf, attnT, kbuf);
  // 10. hs = silu(LN(y)*(1+scale)+shift) -> bf16 into xnbf (xn dead)
  modln<<<MROWS, 256, 0, stream>>>(kbuf, sg, sb, embout, xnbf);
  // 11. out = hs @ Wo + bo + x
  gemm_mfma<512, true, false, false><<<dim3(4, 512), 256, 0, stream>>>(xnbf, wot, bo, x, out);
}

// Round 4
// 926.277 us; speedup vs baseline: 1.4649x; 1.0160x over previous
//
#include <hip/hip_runtime.h>
#include <math.h>

#define B_ 32
#define T_ 2048
#define N_ 2048
#define D_ 512
#define L_ 256
#define TE_ 1024
#define H_ 8
#define MROWS 65536  // B*T = B*N
#define KCH 16       // n-chunks for kstats partial reduction
#define NC_ 8        // n-chunks for attn partial accumulation

typedef __attribute__((ext_vector_type(8))) short short8;
typedef __attribute__((ext_vector_type(4))) float f32x4;

__device__ __forceinline__ unsigned short f2bf(float f) {
  unsigned u = __float_as_uint(f);
  unsigned r = (u + 0x7FFF + ((u >> 16) & 1)) >> 16;  // RNE
  return (unsigned short)r;
}
__device__ __forceinline__ float bf2f(unsigned short u) {
  return __uint_as_float(((unsigned)u) << 16);
}
__device__ __forceinline__ void gload_lds16(const void* g, void* l) {
  __builtin_amdgcn_global_load_lds(
      (const __attribute__((address_space(1))) void*)g,
      (__attribute__((address_space(3))) void*)l, 16, 0, 0);
}

// ---------------- block reduce (256 threads) ----------------
__device__ __forceinline__ float blockReduceSum(float v, float* ws) {
#pragma unroll
  for (int m = 32; m >= 1; m >>= 1) v += __shfl_xor(v, m, 64);
  int wid = threadIdx.x >> 6;
  int lane = threadIdx.x & 63;
  __syncthreads();
  if (lane == 0) ws[wid] = v;
  __syncthreads();
  return ws[0] + ws[1] + ws[2] + ws[3];
}

// ---------------- row LayerNorm -> bf16 ----------------
template <int COLS>
__global__ void __launch_bounds__(256) ln_rows(const float* __restrict__ in,
                                               const float* __restrict__ g,
                                               const float* __restrict__ bb,
                                               unsigned short* __restrict__ out) {
  constexpr int E = COLS / 256;
  __shared__ float ws[4];
  size_t row = blockIdx.x;
  const float* rp = in + row * COLS;
  float v[E];
  float s = 0.f;
#pragma unroll
  for (int e = 0; e < E; ++e) {
    v[e] = rp[threadIdx.x + e * 256];
    s += v[e];
  }
  s = blockReduceSum(s, ws);
  float mean = s * (1.0f / COLS);
  float q = 0.f;
#pragma unroll
  for (int e = 0; e < E; ++e) {
    float d = v[e] - mean;
    q += d * d;
  }
  q = blockReduceSum(q, ws);
  float rstd = rsqrtf(q * (1.0f / COLS) + 1e-5f);
  unsigned short* op = out + row * COLS;
#pragma unroll
  for (int e = 0; e < E; ++e) {
    int c = threadIdx.x + e * 256;
    op[c] = f2bf((v[e] - mean) * rstd * g[c] + bb[c]);
  }
}

// ---------------- weight transpose + cast: Wt[n][k] = bf16(W[k][n]) ----------------
__global__ void __launch_bounds__(256) transcast(const float* __restrict__ W,
                                                 unsigned short* __restrict__ Wt,
                                                 int K, int Ncols) {
  __shared__ float t[32][33];
  int k0 = blockIdx.x * 32, n0 = blockIdx.y * 32;
  int tx = threadIdx.x & 31, ty = threadIdx.x >> 5;  // 32 x 8
#pragma unroll
  for (int i = 0; i < 32; i += 8)
    t[ty + i][tx] = W[(size_t)(k0 + ty + i) * Ncols + n0 + tx];
  __syncthreads();
#pragma unroll
  for (int i = 0; i < 32; i += 8)
    Wt[(size_t)(n0 + ty + i) * K + k0 + tx] = f2bf(t[tx][ty + i]);
}

// ---------------- bf16 MFMA GEMM: C[M,512] = A[M,KT] @ Wt[512,KT]^T + bias (+add) ----------------
// 128x128 tile, 4 waves in 2x2, each wave 64x64 as 4x4 of 16x16x32 MFMA.
// Double-buffered prefetch: STAGE(t+1) issued before COMPUTE(t); 1 barrier per K-step.
// QSM: apply softmax over each 64-col group (head) on the fp32 acc before bf16 store.
template <int KT, bool ADD, bool OUTBF, bool QSM>
__global__ void __launch_bounds__(256) gemm_mfma(const unsigned short* __restrict__ A,
                                                 const unsigned short* __restrict__ Wt,
                                                 const float* __restrict__ bias,
                                                 const float* __restrict__ add,
                                                 void* __restrict__ Cv) {
  __shared__ __align__(16) unsigned short sA[2][128 * 32];
  __shared__ __align__(16) unsigned short sB[2][128 * 32];
  int tid = threadIdx.x;
  int w = tid >> 6, lane = tid & 63;
  int quad = lane >> 4, r16 = lane & 15;
  int wr = w >> 1, wc = w & 1;
  size_t m0 = (size_t)blockIdx.y * 128;
  int n0 = blockIdx.x * 128;
  int srow = lane >> 2;        // 0..15
  int scol = (lane & 3) * 8;   // ushort offset within 32-wide K slice
  f32x4 acc[4][4] = {};

  const unsigned short* Arow0 = &A[(m0 + w * 32 + srow) * KT + scol];
  const unsigned short* Brow0 = &Wt[(size_t)(n0 + w * 32 + srow) * KT + scol];

#define G_STAGE(buf, k0)                                                          \
  do {                                                                            \
    gload_lds16(Arow0 + (k0), &sA[buf][(w * 2 + 0) * 512]);                       \
    gload_lds16(Arow0 + (size_t)16 * KT + (k0), &sA[buf][(w * 2 + 1) * 512]);     \
    gload_lds16(Brow0 + (k0), &sB[buf][(w * 2 + 0) * 512]);                       \
    gload_lds16(Brow0 + (size_t)16 * KT + (k0), &sB[buf][(w * 2 + 1) * 512]);     \
  } while (0)

#define G_COMPUTE(buf)                                                            \
  do {                                                                            \
    short8 af[4], bfr[4];                                                         \
    _Pragma("unroll") for (int mi = 0; mi < 4; ++mi)                              \
        af[mi] = *(const short8*)&sA[buf][(wr * 64 + mi * 16 + r16) * 32 + quad * 8]; \
    _Pragma("unroll") for (int ni = 0; ni < 4; ++ni)                              \
        bfr[ni] = *(const short8*)&sB[buf][(wc * 64 + ni * 16 + r16) * 32 + quad * 8]; \
    _Pragma("unroll") for (int mi = 0; mi < 4; ++mi)                              \
        _Pragma("unroll") for (int ni = 0; ni < 4; ++ni)                          \
            acc[mi][ni] =                                                         \
                __builtin_amdgcn_mfma_f32_16x16x32_bf16(af[mi], bfr[ni], acc[mi][ni], 0, 0, 0); \
  } while (0)

  constexpr int NT = KT / 32;  // even (8 or 16)
  G_STAGE(0, 0);
  __syncthreads();  // drain prologue stage
#pragma unroll 1
  for (int t = 0; t < NT; t += 2) {
    if (t + 1 < NT) G_STAGE(1, (t + 1) * 32);
    G_COMPUTE(0);
    __syncthreads();  // drains stage(1); all waves done reading buf0
    if (t + 2 < NT) G_STAGE(0, (t + 2) * 32);
    G_COMPUTE(1);
    __syncthreads();  // drains stage(0); all waves done reading buf1
  }
#undef G_STAGE
#undef G_COMPUTE

  float* Cf = (float*)Cv;
  unsigned short* Cb = (unsigned short*)Cv;
#pragma unroll
  for (int mi = 0; mi < 4; ++mi)
#pragma unroll
    for (int r = 0; r < 4; ++r) {
      size_t grow = m0 + wr * 64 + mi * 16 + quad * 4 + r;
      if constexpr (QSM) {
        // wave's 64 cols = one head; row's 64 vals live in 16 lanes x 4 regs.
        float v4[4];
        float mx = -1e30f;
#pragma unroll
        for (int ni = 0; ni < 4; ++ni) {
          v4[ni] = acc[mi][ni][r] + bias[n0 + wc * 64 + ni * 16 + r16];
          mx = fmaxf(mx, v4[ni]);
        }
#pragma unroll
        for (int s = 8; s >= 1; s >>= 1) mx = fmaxf(mx, __shfl_xor(mx, s, 64));
        float ssum = 0.f;
#pragma unroll
        for (int ni = 0; ni < 4; ++ni) {
          v4[ni] = expf(v4[ni] - mx);
          ssum += v4[ni];
        }
#pragma unroll
        for (int s = 8; s >= 1; s >>= 1) ssum += __shfl_xor(ssum, s, 64);
        float inv = 1.f / ssum;
#pragma unroll
        for (int ni = 0; ni < 4; ++ni) {
          int gcol = n0 + wc * 64 + ni * 16 + r16;
          Cb[grow * 512 + gcol] = f2bf(v4[ni] * inv);
        }
      } else {
#pragma unroll
        for (int ni = 0; ni < 4; ++ni) {
          int gcol = n0 + wc * 64 + ni * 16 + r16;
          float val = acc[mi][ni][r] + bias[gcol];
          if constexpr (ADD) val += add[grow * 512 + gcol];
          if constexpr (OUTBF)
            Cb[grow * 512 + gcol] = f2bf(val);
          else
            Cf[grow * 512 + gcol] = val;
        }
      }
    }
}

// ---------------- k softmax partial stats over an n-chunk (per b, channel) ----------------
__global__ void __launch_bounds__(256) kstats_part(const float* __restrict__ k,
                                                   float* __restrict__ pmax,
                                                   float* __restrict__ psum) {
  int b = blockIdx.x, cg = blockIdx.y, ch = blockIdx.z;
  int tid = threadIdx.x;
  int lane = tid & 63, slice = tid >> 6;  // 4 slices over rows
  int c = cg * 64 + lane;
  constexpr int ROWS = N_ / KCH;          // 128
  constexpr int PT = ROWS / 4;            // 32 values per thread
  const float* kp = k + ((size_t)b * N_ + (size_t)ch * ROWS) * D_ + c;
  float v[PT];
#pragma unroll
  for (int i = 0; i < PT; ++i) v[i] = kp[(size_t)(slice + i * 4) * D_];
  float m = v[0];
#pragma unroll
  for (int i = 1; i < PT; ++i) m = fmaxf(m, v[i]);
  float s = 0.f;
#pragma unroll
  for (int i = 0; i < PT; ++i) s += expf(v[i] - m);
  __shared__ float mred[256], sred[256];
  mred[tid] = m;
  sred[tid] = s;
  __syncthreads();
  if (tid < 64) {
    float m0 = mred[tid], m1 = mred[tid + 64], m2 = mred[tid + 128], m3 = mred[tid + 192];
    float mm = fmaxf(fmaxf(m0, m1), fmaxf(m2, m3));
    float ss = sred[tid] * expf(m0 - mm) + sred[tid + 64] * expf(m1 - mm) +
               sred[tid + 128] * expf(m2 - mm) + sred[tid + 192] * expf(m3 - mm);
    pmax[((size_t)b * KCH + ch) * D_ + cg * 64 + tid] = mm;
    psum[((size_t)b * KCH + ch) * D_ + cg * 64 + tid] = ss;
  }
}

// ---------------- combine KCH partial stats -> kmax/ksum ----------------
__global__ void __launch_bounds__(256) kstats_comb(const float* __restrict__ pmax,
                                                   const float* __restrict__ psum,
                                                   float* __restrict__ kmax,
                                                   float* __restrict__ ksum) {
  int b = blockIdx.x;
  int c = blockIdx.y * 256 + threadIdx.x;
  float pm[KCH];
#pragma unroll
  for (int ch = 0; ch < KCH; ++ch) pm[ch] = pmax[((size_t)b * KCH + ch) * D_ + c];
  float m = pm[0];
#pragma unroll
  for (int ch = 1; ch < KCH; ++ch) m = fmaxf(m, pm[ch]);
  float s = 0.f;
#pragma unroll
  for (int ch = 0; ch < KCH; ++ch)
    s += psum[((size_t)b * KCH + ch) * D_ + c] * expf(pm[ch] - m);
  kmax[b * D_ + c] = m;
  ksum[b * D_ + c] = s;
}

// ---------------- attn_part[b,h,nc] = softmax(k)^T @ v over an n-chunk of 256 ----------------
// Register-prefetch: chunk c+1's global loads issue during chunk c's compute.
__global__ void __launch_bounds__(256) attn_part_kernel(const float* __restrict__ k,
                                                        const float* __restrict__ v,
                                                        const float* __restrict__ kmax,
                                                        const float* __restrict__ ksum,
                                                        float* __restrict__ part) {
  int b = blockIdx.x, h = blockIdx.y, nc = blockIdx.z;
  int tid = threadIdx.x;
  __shared__ float ks_[32][68];
  __shared__ float vs_[32][68];
  __shared__ float mx[64], is_[64];
  if (tid < 64) {
    mx[tid] = kmax[b * D_ + h * 64 + tid];
    is_[tid] = 1.f / ksum[b * D_ + h * 64 + tid];
  }
  const float* kp = k + ((size_t)b * N_ + nc * 256) * D_ + h * 64;
  const float* vp = v + ((size_t)b * N_ + nc * 256) * D_ + h * 64;
  float acc[4][4] = {};
  int tx = tid & 15, ty = tid >> 4;
  int lr = tid >> 4;
  int c4 = (tid & 15) * 4;
  float4 kv0, vv0, kv1, vv1;
  kv0 = *(const float4*)&kp[(size_t)lr * D_ + c4];
  vv0 = *(const float4*)&vp[(size_t)lr * D_ + c4];
  kv1 = *(const float4*)&kp[(size_t)(lr + 16) * D_ + c4];
  vv1 = *(const float4*)&vp[(size_t)(lr + 16) * D_ + c4];
  for (int n0 = 0; n0 < 256; n0 += 32) {
    __syncthreads();  // previous compute done; LDS writable (also covers mx/is_ first time)
    ks_[lr][c4 + 0] = expf(kv0.x - mx[c4 + 0]) * is_[c4 + 0];
    ks_[lr][c4 + 1] = expf(kv0.y - mx[c4 + 1]) * is_[c4 + 1];
    ks_[lr][c4 + 2] = expf(kv0.z - mx[c4 + 2]) * is_[c4 + 2];
    ks_[lr][c4 + 3] = expf(kv0.w - mx[c4 + 3]) * is_[c4 + 3];
    vs_[lr][c4 + 0] = vv0.x;
    vs_[lr][c4 + 1] = vv0.y;
    vs_[lr][c4 + 2] = vv0.z;
    vs_[lr][c4 + 3] = vv0.w;
    ks_[lr + 16][c4 + 0] = expf(kv1.x - mx[c4 + 0]) * is_[c4 + 0];
    ks_[lr + 16][c4 + 1] = expf(kv1.y - mx[c4 + 1]) * is_[c4 + 1];
    ks_[lr + 16][c4 + 2] = expf(kv1.z - mx[c4 + 2]) * is_[c4 + 2];
    ks_[lr + 16][c4 + 3] = expf(kv1.w - mx[c4 + 3]) * is_[c4 + 3];
    vs_[lr + 16][c4 + 0] = vv1.x;
    vs_[lr + 16][c4 + 1] = vv1.y;
    vs_[lr + 16][c4 + 2] = vv1.z;
    vs_[lr + 16][c4 + 3] = vv1.w;
    if (n0 + 32 < 256) {  // prefetch next chunk; latency hides under compute below
      kv0 = *(const float4*)&kp[(size_t)(n0 + 32 + lr) * D_ + c4];
      vv0 = *(const float4*)&vp[(size_t)(n0 + 32 + lr) * D_ + c4];
      kv1 = *(const float4*)&kp[(size_t)(n0 + 48 + lr) * D_ + c4];
      vv1 = *(const float4*)&vp[(size_t)(n0 + 48 + lr) * D_ + c4];
    }
    __syncthreads();
#pragma unroll
    for (int nn = 0; nn < 32; ++nn) {
      float av[4], bv2[4];
#pragma unroll
      for (int i = 0; i < 4; ++i) av[i] = ks_[nn][ty * 4 + i];
#pragma unroll
      for (int j = 0; j < 4; ++j) bv2[j] = vs_[nn][tx * 4 + j];
#pragma unroll
      for (int i = 0; i < 4; ++i)
#pragma unroll
        for (int j = 0; j < 4; ++j) acc[i][j] += av[i] * bv2[j];
    }
  }
  float* ap = part + ((size_t)(b * H_ + h) * NC_ + nc) * 4096;
#pragma unroll
  for (int i = 0; i < 4; ++i) {
    float4 st = make_float4(acc[i][0], acc[i][1], acc[i][2], acc[i][3]);
    *(float4*)&ap[(ty * 4 + i) * 64 + tx * 4] = st;
  }
}

// ---------------- reduce NC_ partials -> attnT (bf16, transposed: [l][d]) ----------------
__global__ void __launch_bounds__(256) attn_reduce(const float* __restrict__ part,
                                                   unsigned short* __restrict__ attnT) {
  size_t o = ((size_t)blockIdx.x * 256 + threadIdx.x) * 4;  // 1M elements total
  size_t bh = o >> 12;
  size_t e = o & 4095;
  float4 s = make_float4(0.f, 0.f, 0.f, 0.f);
#pragma unroll
  for (int nc = 0; nc < NC_; ++nc) {
    float4 p = *(const float4*)&part[(bh * NC_ + nc) * 4096 + e];
    s.x += p.x;
    s.y += p.y;
    s.z += p.z;
    s.w += p.w;
  }
  // part element e = d*64 + l  (attn[d][l]); emit attnT[l][d] in bf16
  int d = (int)(e >> 6);
  int l = (int)(e & 63);
  unsigned short* ab = attnT + bh * 4096;
  ab[(l + 0) * 64 + d] = f2bf(s.x);
  ab[(l + 1) * 64 + d] = f2bf(s.y);
  ab[(l + 2) * 64 + d] = f2bf(s.z);
  ab[(l + 3) * 64 + d] = f2bf(s.w);
}

// ---------------- emb modulation: eo = silu(emb) @ We + be ----------------
__global__ void __launch_bounds__(256) embmod(const float* __restrict__ emb,
                                              const float* __restrict__ We,
                                              const float* __restrict__ be,
                                              float* __restrict__ eo) {
  int b = blockIdx.x, tid = threadIdx.x;
  __shared__ float se[TE_];
  for (int i = tid; i < TE_; i += 256) {
    float e = emb[b * TE_ + i];
    se[i] = e / (1.f + expf(-e));
  }
  __syncthreads();
  int j0 = tid * 4;
  float a0 = 0, a1 = 0, a2 = 0, a3 = 0;
  for (int i = 0; i < TE_; ++i) {
    float s = se[i];
    float4 wv = *(const float4*)&We[(size_t)i * 1024 + j0];
    a0 += s * wv.x;
    a1 += s * wv.y;
    a2 += s * wv.z;
    a3 += s * wv.w;
  }
  eo[b * 1024 + j0 + 0] = a0 + be[j0 + 0];
  eo[b * 1024 + j0 + 1] = a1 + be[j0 + 1];
  eo[b * 1024 + j0 + 2] = a2 + be[j0 + 2];
  eo[b * 1024 + j0 + 3] = a3 + be[j0 + 3];
}

// ---------------- y = qsm @ attnT^T via MFMA: per block 256 rows x 64 cols (one head) ----
// Both K-halves staged up front into separate buffers; single barrier, no re-staging.
__global__ void __launch_bounds__(256) yein_mfma(const unsigned short* __restrict__ qsm,
                                                 const unsigned short* __restrict__ attnT,
                                                 float* __restrict__ y) {
  int b = blockIdx.z, h = blockIdx.y;
  size_t t0 = (size_t)blockIdx.x * 256;
  int tid = threadIdx.x;
  int w = tid >> 6, lane = tid & 63;
  int quad = lane >> 4, r16 = lane & 15;
  int srow = lane >> 2;
  int scol = (lane & 3) * 8;
  __shared__ __align__(16) unsigned short sA[2][256 * 32];  // 32 KB
  __shared__ __align__(16) unsigned short sB[2][64 * 32];   // 8 KB
  const unsigned short* qp = qsm + ((size_t)b * T_ + t0) * D_ + h * 64;
  const unsigned short* bp = attnT + (size_t)(b * H_ + h) * 4096;
  f32x4 acc[4][4] = {};

#pragma unroll
  for (int half = 0; half < 2; ++half) {
    int k0 = half * 32;
#pragma unroll
    for (int i = 0; i < 4; ++i) {
      int seg = w * 4 + i;  // 0..15, 16 rows each
      gload_lds16(&qp[(size_t)(seg * 16 + srow) * D_ + k0 + scol], &sA[half][seg * 512]);
    }
    gload_lds16(&bp[(w * 16 + srow) * 64 + k0 + scol], &sB[half][w * 512]);
  }
  __syncthreads();
#pragma unroll
  for (int half = 0; half < 2; ++half) {
    short8 af[4], bfr[4];
#pragma unroll
    for (int mi = 0; mi < 4; ++mi)
      af[mi] = *(const short8*)&sA[half][(w * 64 + mi * 16 + r16) * 32 + quad * 8];
#pragma unroll
    for (int ni = 0; ni < 4; ++ni)
      bfr[ni] = *(const short8*)&sB[half][(ni * 16 + r16) * 32 + quad * 8];
#pragma unroll
    for (int mi = 0; mi < 4; ++mi)
#pragma unroll
      for (int ni = 0; ni < 4; ++ni)
        acc[mi][ni] = __builtin_amdgcn_mfma_f32_16x16x32_bf16(af[mi], bfr[ni], acc[mi][ni], 0, 0, 0);
  }

#pragma unroll
  for (int mi = 0; mi < 4; ++mi)
#pragma unroll
    for (int r = 0; r < 4; ++r) {
      size_t grow = t0 + w * 64 + mi * 16 + quad * 4 + r;
      float* yp = y + ((size_t)b * T_ + grow) * D_ + h * 64;
#pragma unroll
      for (int ni = 0; ni < 4; ++ni) yp[ni * 16 + r16] = acc[mi][ni][r];
    }
}

// ---------------- LN(y) * (1+scale) + shift, then silu -> bf16 ----------------
__global__ void __launch_bounds__(256) modln(const float* __restrict__ y,
                                             const float* __restrict__ sg,
                                             const float* __restrict__ sb,
                                             const float* __restrict__ eo,
                                             unsigned short* __restrict__ hs) {
  __shared__ float ws[4];
  size_t row = blockIdx.x;
  int b = (int)(row >> 11);
  const float* rp = y + row * D_;
  float v[2];
  float s = 0.f;
#pragma unroll
  for (int e = 0; e < 2; ++e) {
    v[e] = rp[threadIdx.x + e * 256];
    s += v[e];
  }
  s = blockReduceSum(s, ws);
  float mean = s * (1.0f / D_);
  float q = 0.f;
#pragma unroll
  for (int e = 0; e < 2; ++e) {
    float d = v[e] - mean;
    q += d * d;
  }
  q = blockReduceSum(q, ws);
  float rstd = rsqrtf(q * (1.0f / D_) + 1e-5f);
#pragma unroll
  for (int e = 0; e < 2; ++e) {
    int c = threadIdx.x + e * 256;
    float xm = (v[e] - mean) * rstd * sg[c] + sb[c];
    float sc = eo[b * 1024 + c];
    float sh = eo[b * 1024 + D_ + c];
    float hm = xm * (1.f + sc) + sh;
    hs[row * D_ + c] = f2bf(hm / (1.f + expf(-hm)));
  }
}

extern "C" void kernel_launch(void* const* d_in, const int* in_sizes, int n_in,
                              void* d_out, int out_size, void* d_ws, size_t ws_size,
                              hipStream_t stream) {
  const float* x = (const float*)d_in[0];
  const float* xf = (const float*)d_in[1];
  const float* emb = (const float*)d_in[2];
  const float* norm_g = (const float*)d_in[3];
  const float* norm_b = (const float*)d_in[4];
  const float* tnorm_g = (const float*)d_in[5];
  const float* tnorm_b = (const float*)d_in[6];
  const float* Wq = (const float*)d_in[7];
  const float* bq = (const float*)d_in[8];
  const float* Wk = (const float*)d_in[9];
  const float* bk = (const float*)d_in[10];
  const float* Wv = (const float*)d_in[11];
  const float* bv = (const float*)d_in[12];
  const float* We = (const float*)d_in[13];
  const float* be = (const float*)d_in[14];
  const float* sg = (const float*)d_in[15];
  const float* sb = (const float*)d_in[16];
  const float* Wo = (const float*)d_in[17];
  const float* bo = (const float*)d_in[18];
  float* out = (float*)d_out;

  float* w = (float*)d_ws;
  // layout (floats):
  unsigned short* qbf = (unsigned short*)w;               // 33.5M ushort = 16.78M floats
  float* kbuf = w + 16777216;                             // 33.5M floats (k -> y)
  float* vbuf = w + 16777216 + 33554432;                  // 33.5M floats
  unsigned short* xnbf = (unsigned short*)(w + 83886080); // 33.5M ushort (xn -> hs)
  unsigned short* xfnbf = (unsigned short*)(w + 100663296); // 16.78M ushort
  unsigned short* attnT = (unsigned short*)(w + 109051904); // 1M ushort (bf16, [l][d])
  float* kmaxp = w + 109051904 + 1048576;                 // 16384
  float* ksump = kmaxp + 16384;                           // 16384
  float* embout = ksump + 16384;                          // 32768
  unsigned short* wqt = (unsigned short*)(embout + 32768);  // 512*512
  unsigned short* wkt = wqt + 262144;                       // 512*256
  unsigned short* wvt = wkt + 131072;                       // 512*256
  unsigned short* wot = wvt + 131072;                       // 512*512
  // kstats partials: reuse the xnbf float region (dead between step 2 and step 11)
  float* pmaxp = w + 83886080;                            // 32*KCH*512 floats
  float* psump = pmaxp + (size_t)B_ * KCH * D_;           // 32*KCH*512 floats
  // attn partials: reuse the xfnbf region (dead after step 5)
  float* attnpart = w + 100663296;

  // 0. weight transpose-casts (tiny)
  transcast<<<dim3(16, 16), 256, 0, stream>>>(Wq, wqt, 512, 512);
  transcast<<<dim3(8, 16), 256, 0, stream>>>(Wk, wkt, 256, 512);
  transcast<<<dim3(8, 16), 256, 0, stream>>>(Wv, wvt, 256, 512);
  transcast<<<dim3(16, 16), 256, 0, stream>>>(Wo, wot, 512, 512);
  // 1. xn = LN(x) -> bf16
  ln_rows<512><<<MROWS, 256, 0, stream>>>(x, norm_g, norm_b, xnbf);
  // 2. qsm = softmax(xn @ Wq + bq) -> bf16 (softmax fused in epilogue, fp32 acc)
  gemm_mfma<512, false, true, true><<<dim3(4, 512), 256, 0, stream>>>(xnbf, wqt, bq, nullptr, qbf);
  // 3. xfn = LN(xf) -> bf16
  ln_rows<256><<<MROWS, 256, 0, stream>>>(xf, tnorm_g, tnorm_b, xfnbf);
  // 4. k = xfn @ Wk + bk -> fp32
  gemm_mfma<256, false, false, false><<<dim3(4, 512), 256, 0, stream>>>(xfnbf, wkt, bk, nullptr, kbuf);
  // 5. v = xfn @ Wv + bv -> fp32
  gemm_mfma<256, false, false, false><<<dim3(4, 512), 256, 0, stream>>>(xfnbf, wvt, bv, nullptr, vbuf);
  // 6. k softmax stats: chunked partials (16 n-chunks) + combine
  kstats_part<<<dim3(32, 8, KCH), 256, 0, stream>>>(kbuf, pmaxp, psump);
  kstats_comb<<<dim3(32, 2), 256, 0, stream>>>(pmaxp, psump, kmaxp, ksump);
  // 7. attn partials (no atomics) + reduce -> attnT bf16
  attn_part_kernel<<<dim3(32, 8, NC_), 256, 0, stream>>>(kbuf, vbuf, kmaxp, ksump, attnpart);
  attn_reduce<<<1024, 256, 0, stream>>>(attnpart, attnT);
  // 8. emb modulation
  embmod<<<32, 256, 0, stream>>>(emb, We, be, embout);
  // 9. y = qsm @ attn -> kbuf (k dead) via MFMA
  yein_mfma<<<dim3(8, 8, 32), 256, 0, stream>>>(qbf, attnT, kbuf);
  // 10. hs = silu(LN(y)*(1+scale)+shift) -> bf16 into xnbf (xn dead)
  modln<<<MROWS, 256, 0, stream>>>(kbuf, sg, sb, embout, xnbf);
  // 11. out = hs @ Wo + bo + x
  gemm_mfma<512, true, false, false><<<dim3(4, 512), 256, 0, stream>>>(xnbf, wot, bo, x, out);
}

// Round 5
// 904.544 us; speedup vs baseline: 1.5001x; 1.0240x over previous
//
#include <hip/hip_runtime.h>
#include <math.h>

#define B_ 32
#define T_ 2048
#define N_ 2048
#define D_ 512
#define L_ 256
#define TE_ 1024
#define H_ 8
#define MROWS 65536  // B*T = B*N
#define KCH 16       // n-chunks for k softmax stats (= rows-per-b / 128)
#define NC_ 8        // n-chunks for attn partial accumulation

typedef __attribute__((ext_vector_type(8))) short short8;
typedef __attribute__((ext_vector_type(4))) float f32x4;
typedef __attribute__((ext_vector_type(4))) unsigned short us4;

__device__ __forceinline__ unsigned short f2bf(float f) {
  unsigned u = __float_as_uint(f);
  unsigned r = (u + 0x7FFF + ((u >> 16) & 1)) >> 16;  // RNE
  return (unsigned short)r;
}
__device__ __forceinline__ float bf2f(unsigned short u) {
  return __uint_as_float(((unsigned)u) << 16);
}
__device__ __forceinline__ void gload_lds16(const void* g, void* l) {
  __builtin_amdgcn_global_load_lds(
      (const __attribute__((address_space(1))) void*)g,
      (__attribute__((address_space(3))) void*)l, 16, 0, 0);
}

// ---------------- block reduce (256 threads) ----------------
__device__ __forceinline__ float blockReduceSum(float v, float* ws) {
#pragma unroll
  for (int m = 32; m >= 1; m >>= 1) v += __shfl_xor(v, m, 64);
  int wid = threadIdx.x >> 6;
  int lane = threadIdx.x & 63;
  __syncthreads();
  if (lane == 0) ws[wid] = v;
  __syncthreads();
  return ws[0] + ws[1] + ws[2] + ws[3];
}

// ---------------- row LayerNorm -> bf16 ----------------
template <int COLS>
__global__ void __launch_bounds__(256) ln_rows(const float* __restrict__ in,
                                               const float* __restrict__ g,
                                               const float* __restrict__ bb,
                                               unsigned short* __restrict__ out) {
  constexpr int E = COLS / 256;
  __shared__ float ws[4];
  size_t row = blockIdx.x;
  const float* rp = in + row * COLS;
  float v[E];
  float s = 0.f;
#pragma unroll
  for (int e = 0; e < E; ++e) {
    v[e] = rp[threadIdx.x + e * 256];
    s += v[e];
  }
  s = blockReduceSum(s, ws);
  float mean = s * (1.0f / COLS);
  float q = 0.f;
#pragma unroll
  for (int e = 0; e < E; ++e) {
    float d = v[e] - mean;
    q += d * d;
  }
  q = blockReduceSum(q, ws);
  float rstd = rsqrtf(q * (1.0f / COLS) + 1e-5f);
  unsigned short* op = out + row * COLS;
#pragma unroll
  for (int e = 0; e < E; ++e) {
    int c = threadIdx.x + e * 256;
    op[c] = f2bf((v[e] - mean) * rstd * g[c] + bb[c]);
  }
}

// ---------------- all weight transpose + casts in one launch ----------------
__global__ void __launch_bounds__(256) transcast_all(const float* __restrict__ Wq,
                                                     const float* __restrict__ Wk,
                                                     const float* __restrict__ Wv,
                                                     const float* __restrict__ Wo,
                                                     unsigned short* __restrict__ wqt,
                                                     unsigned short* __restrict__ wkt,
                                                     unsigned short* __restrict__ wvt,
                                                     unsigned short* __restrict__ wot) {
  int z = blockIdx.z;
  const float* W;
  unsigned short* Wt;
  int K;
  if (z == 0) { W = Wq; Wt = wqt; K = 512; }
  else if (z == 1) { W = Wk; Wt = wkt; K = 256; }
  else if (z == 2) { W = Wv; Wt = wvt; K = 256; }
  else { W = Wo; Wt = wot; K = 512; }
  int k0 = blockIdx.x * 32, n0 = blockIdx.y * 32;
  if (k0 >= K) return;
  __shared__ float t[32][33];
  int tx = threadIdx.x & 31, ty = threadIdx.x >> 5;  // 32 x 8
#pragma unroll
  for (int i = 0; i < 32; i += 8)
    t[ty + i][tx] = W[(size_t)(k0 + ty + i) * 512 + n0 + tx];
  __syncthreads();
#pragma unroll
  for (int i = 0; i < 32; i += 8)
    Wt[(size_t)(n0 + ty + i) * K + k0 + tx] = f2bf(t[tx][ty + i]);
}

// ---------------- bf16 MFMA GEMM: C[M,512] = A[M,KT] @ Wt[512,KT]^T + bias (+add) ----------------
// 128x128 tile, 4 waves in 2x2, each wave 64x64 as 4x4 of 16x16x32 MFMA. Double-buffered.
// QSM: softmax over each 64-col head group on fp32 acc, bf16 out.
// KSTATS: bf16 out + per-column (over the 128-row tile) softmax stats on the ROUNDED values.
template <int KT, bool ADD, bool OUTBF, bool QSM, bool KSTATS>
__global__ void __launch_bounds__(256) gemm_mfma(const unsigned short* __restrict__ A,
                                                 const unsigned short* __restrict__ Wt,
                                                 const float* __restrict__ bias,
                                                 const float* __restrict__ add,
                                                 void* __restrict__ Cv,
                                                 float* __restrict__ pmaxO,
                                                 float* __restrict__ psumO) {
  __shared__ __align__(16) unsigned short sA[2][128 * 32];
  __shared__ __align__(16) unsigned short sB[2][128 * 32];
  int tid = threadIdx.x;
  int w = tid >> 6, lane = tid & 63;
  int quad = lane >> 4, r16 = lane & 15;
  int wr = w >> 1, wc = w & 1;
  size_t m0 = (size_t)blockIdx.y * 128;
  int n0 = blockIdx.x * 128;
  int srow = lane >> 2;        // 0..15
  int scol = (lane & 3) * 8;   // ushort offset within 32-wide K slice
  f32x4 acc[4][4] = {};

  const unsigned short* Arow0 = &A[(m0 + w * 32 + srow) * KT + scol];
  const unsigned short* Brow0 = &Wt[(size_t)(n0 + w * 32 + srow) * KT + scol];

#define G_STAGE(buf, k0)                                                          \
  do {                                                                            \
    gload_lds16(Arow0 + (k0), &sA[buf][(w * 2 + 0) * 512]);                       \
    gload_lds16(Arow0 + (size_t)16 * KT + (k0), &sA[buf][(w * 2 + 1) * 512]);     \
    gload_lds16(Brow0 + (k0), &sB[buf][(w * 2 + 0) * 512]);                       \
    gload_lds16(Brow0 + (size_t)16 * KT + (k0), &sB[buf][(w * 2 + 1) * 512]);     \
  } while (0)

#define G_COMPUTE(buf)                                                            \
  do {                                                                            \
    short8 af[4], bfr[4];                                                         \
    _Pragma("unroll") for (int mi = 0; mi < 4; ++mi)                              \
        af[mi] = *(const short8*)&sA[buf][(wr * 64 + mi * 16 + r16) * 32 + quad * 8]; \
    _Pragma("unroll") for (int ni = 0; ni < 4; ++ni)                              \
        bfr[ni] = *(const short8*)&sB[buf][(wc * 64 + ni * 16 + r16) * 32 + quad * 8]; \
    _Pragma("unroll") for (int mi = 0; mi < 4; ++mi)                              \
        _Pragma("unroll") for (int ni = 0; ni < 4; ++ni)                          \
            acc[mi][ni] =                                                         \
                __builtin_amdgcn_mfma_f32_16x16x32_bf16(af[mi], bfr[ni], acc[mi][ni], 0, 0, 0); \
  } while (0)

  constexpr int NT = KT / 32;  // even (8 or 16)
  G_STAGE(0, 0);
  __syncthreads();
#pragma unroll 1
  for (int t = 0; t < NT; t += 2) {
    if (t + 1 < NT) G_STAGE(1, (t + 1) * 32);
    G_COMPUTE(0);
    __syncthreads();
    if (t + 2 < NT) G_STAGE(0, (t + 2) * 32);
    G_COMPUTE(1);
    __syncthreads();
  }
#undef G_STAGE
#undef G_COMPUTE

  float* Cf = (float*)Cv;
  unsigned short* Cb = (unsigned short*)Cv;

  if constexpr (QSM) {
#pragma unroll
    for (int mi = 0; mi < 4; ++mi)
#pragma unroll
      for (int r = 0; r < 4; ++r) {
        size_t grow = m0 + wr * 64 + mi * 16 + quad * 4 + r;
        float v4[4];
        float mx = -1e30f;
#pragma unroll
        for (int ni = 0; ni < 4; ++ni) {
          v4[ni] = acc[mi][ni][r] + bias[n0 + wc * 64 + ni * 16 + r16];
          mx = fmaxf(mx, v4[ni]);
        }
#pragma unroll
        for (int s = 8; s >= 1; s >>= 1) mx = fmaxf(mx, __shfl_xor(mx, s, 64));
        float ssum = 0.f;
#pragma unroll
        for (int ni = 0; ni < 4; ++ni) {
          v4[ni] = expf(v4[ni] - mx);
          ssum += v4[ni];
        }
#pragma unroll
        for (int s = 8; s >= 1; s >>= 1) ssum += __shfl_xor(ssum, s, 64);
        float inv = 1.f / ssum;
#pragma unroll
        for (int ni = 0; ni < 4; ++ni) {
          int gcol = n0 + wc * 64 + ni * 16 + r16;
          Cb[grow * 512 + gcol] = f2bf(v4[ni] * inv);
        }
      }
  } else if constexpr (KSTATS) {
    float tmax[4], tsum[4];
#pragma unroll
    for (int ni = 0; ni < 4; ++ni) { tmax[ni] = -1e30f; tsum[ni] = 0.f; }
    // pass 1: round, store, track max of the ROUNDED values
#pragma unroll
    for (int mi = 0; mi < 4; ++mi)
#pragma unroll
      for (int r = 0; r < 4; ++r) {
        size_t grow = m0 + wr * 64 + mi * 16 + quad * 4 + r;
#pragma unroll
        for (int ni = 0; ni < 4; ++ni) {
          int gcol = n0 + wc * 64 + ni * 16 + r16;
          unsigned short bv = f2bf(acc[mi][ni][r] + bias[gcol]);
          Cb[grow * 512 + gcol] = bv;
          tmax[ni] = fmaxf(tmax[ni], bf2f(bv));
        }
      }
    // pass 2: sum exp of rounded values
#pragma unroll
    for (int mi = 0; mi < 4; ++mi)
#pragma unroll
      for (int r = 0; r < 4; ++r)
#pragma unroll
        for (int ni = 0; ni < 4; ++ni) {
          int gcol = n0 + wc * 64 + ni * 16 + r16;
          float vr = bf2f(f2bf(acc[mi][ni][r] + bias[gcol]));
          tsum[ni] += expf(vr - tmax[ni]);
        }
    // reduce across quads (lanes xor 16, 32)
#pragma unroll
    for (int ni = 0; ni < 4; ++ni) {
#pragma unroll
      for (int mask = 16; mask <= 32; mask <<= 1) {
        float om = __shfl_xor(tmax[ni], mask, 64);
        float os = __shfl_xor(tsum[ni], mask, 64);
        float nm = fmaxf(tmax[ni], om);
        tsum[ni] = tsum[ni] * expf(tmax[ni] - nm) + os * expf(om - nm);
        tmax[ni] = nm;
      }
    }
    __shared__ float smax[4][64], ssum2[4][64];
    if (quad == 0) {
#pragma unroll
      for (int ni = 0; ni < 4; ++ni) {
        smax[w][ni * 16 + r16] = tmax[ni];
        ssum2[w][ni * 16 + r16] = tsum[ni];
      }
    }
    __syncthreads();
    if (w < 2 && quad == 0) {  // waves 0/1 combine with waves 2/3 (other row-half)
      int b = (int)(blockIdx.y >> 4), ch = (int)(blockIdx.y & 15);
#pragma unroll
      for (int ni = 0; ni < 4; ++ni) {
        int i = ni * 16 + r16;
        float m1 = smax[w][i], m2 = smax[w + 2][i];
        float s1 = ssum2[w][i], s2 = ssum2[w + 2][i];
        float nm = fmaxf(m1, m2);
        float ss = s1 * expf(m1 - nm) + s2 * expf(m2 - nm);
        size_t off = ((size_t)(b * KCH + ch)) * D_ + n0 + w * 64 + i;
        pmaxO[off] = nm;
        psumO[off] = ss;
      }
    }
  } else {
#pragma unroll
    for (int mi = 0; mi < 4; ++mi)
#pragma unroll
      for (int r = 0; r < 4; ++r) {
        size_t grow = m0 + wr * 64 + mi * 16 + quad * 4 + r;
#pragma unroll
        for (int ni = 0; ni < 4; ++ni) {
          int gcol = n0 + wc * 64 + ni * 16 + r16;
          float val = acc[mi][ni][r] + bias[gcol];
          if constexpr (ADD) val += add[grow * 512 + gcol];
          if constexpr (OUTBF)
            Cb[grow * 512 + gcol] = f2bf(val);
          else
            Cf[grow * 512 + gcol] = val;
        }
      }
  }
}

// ---------------- attn_part[b,h,nc] = softmax(k)^T @ v over an n-chunk of 256 ----------------
// bf16 k/v inputs; global stats combined in prologue from per-chunk partials.
__global__ void __launch_bounds__(256) attn_part_kernel(const unsigned short* __restrict__ k,
                                                        const unsigned short* __restrict__ v,
                                                        const float* __restrict__ pmax,
                                                        const float* __restrict__ psum,
                                                        float* __restrict__ part) {
  int b = blockIdx.x, h = blockIdx.y, nc = blockIdx.z;
  int tid = threadIdx.x;
  __shared__ float ks_[32][68];
  __shared__ float vs_[32][68];
  __shared__ float mx[64], is_[64];
  int lr = tid >> 4;
  int c4 = (tid & 15) * 4;
  const unsigned short* kp = k + ((size_t)b * N_ + nc * 256) * D_ + h * 64;
  const unsigned short* vp = v + ((size_t)b * N_ + nc * 256) * D_ + h * 64;
  us4 kv0 = *(const us4*)&kp[(size_t)lr * D_ + c4];
  us4 vv0 = *(const us4*)&vp[(size_t)lr * D_ + c4];
  us4 kv1 = *(const us4*)&kp[(size_t)(lr + 16) * D_ + c4];
  us4 vv1 = *(const us4*)&vp[(size_t)(lr + 16) * D_ + c4];
  if (tid < 64) {
    int c = h * 64 + tid;
    float m = -1e30f, s = 0.f;
#pragma unroll
    for (int ch = 0; ch < KCH; ++ch) {
      float pm = pmax[((size_t)(b * KCH + ch)) * D_ + c];
      float ps = psum[((size_t)(b * KCH + ch)) * D_ + c];
      float nm = fmaxf(m, pm);
      s = s * expf(m - nm) + ps * expf(pm - nm);
      m = nm;
    }
    mx[tid] = m;
    is_[tid] = 1.f / s;
  }
  float acc[4][4] = {};
  int tx = tid & 15, ty = tid >> 4;
  for (int n0 = 0; n0 < 256; n0 += 32) {
    __syncthreads();  // prev compute done; also publishes mx/is_ on first pass
#pragma unroll
    for (int j = 0; j < 4; ++j) {
      ks_[lr][c4 + j] = expf(bf2f(kv0[j]) - mx[c4 + j]) * is_[c4 + j];
      vs_[lr][c4 + j] = bf2f(vv0[j]);
      ks_[lr + 16][c4 + j] = expf(bf2f(kv1[j]) - mx[c4 + j]) * is_[c4 + j];
      vs_[lr + 16][c4 + j] = bf2f(vv1[j]);
    }
    if (n0 + 32 < 256) {  // prefetch next chunk under compute
      kv0 = *(const us4*)&kp[(size_t)(n0 + 32 + lr) * D_ + c4];
      vv0 = *(const us4*)&vp[(size_t)(n0 + 32 + lr) * D_ + c4];
      kv1 = *(const us4*)&kp[(size_t)(n0 + 48 + lr) * D_ + c4];
      vv1 = *(const us4*)&vp[(size_t)(n0 + 48 + lr) * D_ + c4];
    }
    __syncthreads();
#pragma unroll
    for (int nn = 0; nn < 32; ++nn) {
      float av[4], bv2[4];
#pragma unroll
      for (int i = 0; i < 4; ++i) av[i] = ks_[nn][ty * 4 + i];
#pragma unroll
      for (int j = 0; j < 4; ++j) bv2[j] = vs_[nn][tx * 4 + j];
#pragma unroll
      for (int i = 0; i < 4; ++i)
#pragma unroll
        for (int j = 0; j < 4; ++j) acc[i][j] += av[i] * bv2[j];
    }
  }
  float* ap = part + ((size_t)(b * H_ + h) * NC_ + nc) * 4096;
#pragma unroll
  for (int i = 0; i < 4; ++i) {
    float4 st = make_float4(acc[i][0], acc[i][1], acc[i][2], acc[i][3]);
    *(float4*)&ap[(ty * 4 + i) * 64 + tx * 4] = st;
  }
}

// ---------------- reduce NC_ partials -> attnT (bf16, transposed: [l][d]) ----------------
__global__ void __launch_bounds__(256) attn_reduce(const float* __restrict__ part,
                                                   unsigned short* __restrict__ attnT) {
  size_t o = ((size_t)blockIdx.x * 256 + threadIdx.x) * 4;  // 1M elements total
  size_t bh = o >> 12;
  size_t e = o & 4095;
  float4 s = make_float4(0.f, 0.f, 0.f, 0.f);
#pragma unroll
  for (int nc = 0; nc < NC_; ++nc) {
    float4 p = *(const float4*)&part[(bh * NC_ + nc) * 4096 + e];
    s.x += p.x;
    s.y += p.y;
    s.z += p.z;
    s.w += p.w;
  }
  // part element e = d*64 + l  (attn[d][l]); emit attnT[l][d] in bf16
  int d = (int)(e >> 6);
  int l = (int)(e & 63);
  unsigned short* ab = attnT + bh * 4096;
  ab[(l + 0) * 64 + d] = f2bf(s.x);
  ab[(l + 1) * 64 + d] = f2bf(s.y);
  ab[(l + 2) * 64 + d] = f2bf(s.z);
  ab[(l + 3) * 64 + d] = f2bf(s.w);
}

// ---------------- emb modulation: eo = silu(emb) @ We + be ----------------
__global__ void __launch_bounds__(256) embmod(const float* __restrict__ emb,
                                              const float* __restrict__ We,
                                              const float* __restrict__ be,
                                              float* __restrict__ eo) {
  int b = blockIdx.x, tid = threadIdx.x;
  __shared__ float se[TE_];
  for (int i = tid; i < TE_; i += 256) {
    float e = emb[b * TE_ + i];
    se[i] = e / (1.f + expf(-e));
  }
  __syncthreads();
  int j0 = tid * 4;
  float a0 = 0, a1 = 0, a2 = 0, a3 = 0;
  for (int i = 0; i < TE_; ++i) {
    float s = se[i];
    float4 wv = *(const float4*)&We[(size_t)i * 1024 + j0];
    a0 += s * wv.x;
    a1 += s * wv.y;
    a2 += s * wv.z;
    a3 += s * wv.w;
  }
  eo[b * 1024 + j0 + 0] = a0 + be[j0 + 0];
  eo[b * 1024 + j0 + 1] = a1 + be[j0 + 1];
  eo[b * 1024 + j0 + 2] = a2 + be[j0 + 2];
  eo[b * 1024 + j0 + 3] = a3 + be[j0 + 3];
}

// ---------------- y = qsm @ attnT^T via MFMA: per block 256 rows x 64 cols (one head) ----
__global__ void __launch_bounds__(256) yein_mfma(const unsigned short* __restrict__ qsm,
                                                 const unsigned short* __restrict__ attnT,
                                                 float* __restrict__ y) {
  int b = blockIdx.z, h = blockIdx.y;
  size_t t0 = (size_t)blockIdx.x * 256;
  int tid = threadIdx.x;
  int w = tid >> 6, lane = tid & 63;
  int quad = lane >> 4, r16 = lane & 15;
  int srow = lane >> 2;
  int scol = (lane & 3) * 8;
  __shared__ __align__(16) unsigned short sA[2][256 * 32];  // 32 KB
  __shared__ __align__(16) unsigned short sB[2][64 * 32];   // 8 KB
  const unsigned short* qp = qsm + ((size_t)b * T_ + t0) * D_ + h * 64;
  const unsigned short* bp = attnT + (size_t)(b * H_ + h) * 4096;
  f32x4 acc[4][4] = {};

#pragma unroll
  for (int half = 0; half < 2; ++half) {
    int k0 = half * 32;
#pragma unroll
    for (int i = 0; i < 4; ++i) {
      int seg = w * 4 + i;  // 0..15, 16 rows each
      gload_lds16(&qp[(size_t)(seg * 16 + srow) * D_ + k0 + scol], &sA[half][seg * 512]);
    }
    gload_lds16(&bp[(w * 16 + srow) * 64 + k0 + scol], &sB[half][w * 512]);
  }
  __syncthreads();
#pragma unroll
  for (int half = 0; half < 2; ++half) {
    short8 af[4], bfr[4];
#pragma unroll
    for (int mi = 0; mi < 4; ++mi)
      af[mi] = *(const short8*)&sA[half][(w * 64 + mi * 16 + r16) * 32 + quad * 8];
#pragma unroll
    for (int ni = 0; ni < 4; ++ni)
      bfr[ni] = *(const short8*)&sB[half][(ni * 16 + r16) * 32 + quad * 8];
#pragma unroll
    for (int mi = 0; mi < 4; ++mi)
#pragma unroll
      for (int ni = 0; ni < 4; ++ni)
        acc[mi][ni] = __builtin_amdgcn_mfma_f32_16x16x32_bf16(af[mi], bfr[ni], acc[mi][ni], 0, 0, 0);
  }

#pragma unroll
  for (int mi = 0; mi < 4; ++mi)
#pragma unroll
    for (int r = 0; r < 4; ++r) {
      size_t grow = t0 + w * 64 + mi * 16 + quad * 4 + r;
      float* yp = y + ((size_t)b * T_ + grow) * D_ + h * 64;
#pragma unroll
      for (int ni = 0; ni < 4; ++ni) yp[ni * 16 + r16] = acc[mi][ni][r];
    }
}

// ---------------- LN(y) * (1+scale) + shift, then silu -> bf16 ----------------
__global__ void __launch_bounds__(256) modln(const float* __restrict__ y,
                                             const float* __restrict__ sg,
                                             const float* __restrict__ sb,
                                             const float* __restrict__ eo,
                                             unsigned short* __restrict__ hs) {
  __shared__ float ws[4];
  size_t row = blockIdx.x;
  int b = (int)(row >> 11);
  const float* rp = y + row * D_;
  float v[2];
  float s = 0.f;
#pragma unroll
  for (int e = 0; e < 2; ++e) {
    v[e] = rp[threadIdx.x + e * 256];
    s += v[e];
  }
  s = blockReduceSum(s, ws);
  float mean = s * (1.0f / D_);
  float q = 0.f;
#pragma unroll
  for (int e = 0; e < 2; ++e) {
    float d = v[e] - mean;
    q += d * d;
  }
  q = blockReduceSum(q, ws);
  float rstd = rsqrtf(q * (1.0f / D_) + 1e-5f);
#pragma unroll
  for (int e = 0; e < 2; ++e) {
    int c = threadIdx.x + e * 256;
    float xm = (v[e] - mean) * rstd * sg[c] + sb[c];
    float sc = eo[b * 1024 + c];
    float sh = eo[b * 1024 + D_ + c];
    float hm = xm * (1.f + sc) + sh;
    hs[row * D_ + c] = f2bf(hm / (1.f + expf(-hm)));
  }
}

extern "C" void kernel_launch(void* const* d_in, const int* in_sizes, int n_in,
                              void* d_out, int out_size, void* d_ws, size_t ws_size,
                              hipStream_t stream) {
  const float* x = (const float*)d_in[0];
  const float* xf = (const float*)d_in[1];
  const float* emb = (const float*)d_in[2];
  const float* norm_g = (const float*)d_in[3];
  const float* norm_b = (const float*)d_in[4];
  const float* tnorm_g = (const float*)d_in[5];
  const float* tnorm_b = (const float*)d_in[6];
  const float* Wq = (const float*)d_in[7];
  const float* bq = (const float*)d_in[8];
  const float* Wk = (const float*)d_in[9];
  const float* bk = (const float*)d_in[10];
  const float* Wv = (const float*)d_in[11];
  const float* bv = (const float*)d_in[12];
  const float* We = (const float*)d_in[13];
  const float* be = (const float*)d_in[14];
  const float* sg = (const float*)d_in[15];
  const float* sb = (const float*)d_in[16];
  const float* Wo = (const float*)d_in[17];
  const float* bo = (const float*)d_in[18];
  float* out = (float*)d_out;

  float* w = (float*)d_ws;
  // layout (float offsets):
  unsigned short* qbf = (unsigned short*)w;                  // 33.5M ushort
  unsigned short* kb = (unsigned short*)(w + 16777216);      // 33.5M ushort (bf16 k)
  unsigned short* vb = (unsigned short*)(w + 33554432);      // 33.5M ushort (bf16 v)
  float* ybuf = w + 50331648;                                // 33.5M floats (y)
  unsigned short* xnbf = (unsigned short*)(w + 83886080);    // 33.5M ushort (xn -> hs)
  unsigned short* xfnbf = (unsigned short*)(w + 100663296);  // 16.78M ushort
  float* attnpart = w + 100663296;                           // reuse xfn region (8.39M floats)
  unsigned short* attnT = (unsigned short*)(w + 109051904);  // 1.05M ushort
  float* pmaxp = w + 109051904 + 524288;                     // 262144 floats
  float* psump = pmaxp + 262144;                             // 262144
  float* embout = psump + 262144;                            // 32768
  unsigned short* wqt = (unsigned short*)(embout + 32768);   // 512*512
  unsigned short* wkt = wqt + 262144;                        // 512*256
  unsigned short* wvt = wkt + 131072;                        // 512*256
  unsigned short* wot = wvt + 131072;                        // 512*512

  // 0. all weight transpose-casts (one launch)
  transcast_all<<<dim3(16, 16, 4), 256, 0, stream>>>(Wq, Wk, Wv, Wo, wqt, wkt, wvt, wot);
  // 1. xn = LN(x) -> bf16
  ln_rows<512><<<MROWS, 256, 0, stream>>>(x, norm_g, norm_b, xnbf);
  // 2. qsm = softmax(xn @ Wq + bq) -> bf16
  gemm_mfma<512, false, true, true, false><<<dim3(4, 512), 256, 0, stream>>>(
      xnbf, wqt, bq, nullptr, qbf, nullptr, nullptr);
  // 3. xfn = LN(xf) -> bf16
  ln_rows<256><<<MROWS, 256, 0, stream>>>(xf, tnorm_g, tnorm_b, xfnbf);
  // 4. k = xfn @ Wk + bk -> bf16 + fused per-chunk softmax stats (on rounded values)
  gemm_mfma<256, false, true, false, true><<<dim3(4, 512), 256, 0, stream>>>(
      xfnbf, wkt, bk, nullptr, kb, pmaxp, psump);
  // 5. v = xfn @ Wv + bv -> bf16
  gemm_mfma<256, false, true, false, false><<<dim3(4, 512), 256, 0, stream>>>(
      xfnbf, wvt, bv, nullptr, vb, nullptr, nullptr);
  // 6. attn partials (stats combined in prologue) + reduce -> attnT bf16
  attn_part_kernel<<<dim3(32, 8, NC_), 256, 0, stream>>>(kb, vb, pmaxp, psump, attnpart);
  attn_reduce<<<1024, 256, 0, stream>>>(attnpart, attnT);
  // 7. emb modulation
  embmod<<<32, 256, 0, stream>>>(emb, We, be, embout);
  // 8. y = qsm @ attn -> ybuf via MFMA
  yein_mfma<<<dim3(8, 8, 32), 256, 0, stream>>>(qbf, attnT, ybuf);
  // 9. hs = silu(LN(y)*(1+scale)+shift) -> bf16 into xnbf (xn dead)
  modln<<<MROWS, 256, 0, stream>>>(ybuf, sg, sb, embout, xnbf);
  // 10. out = hs @ Wo + bo + x
  gemm_mfma<512, true, false, false, false><<<dim3(4, 512), 256, 0, stream>>>(
      xnbf, wot, bo, x, out, nullptr, nullptr);
}

// Round 6
// 863.265 us; speedup vs baseline: 1.5719x; 1.0478x over previous
//
#include <hip/hip_runtime.h>
#include <math.h>

#define B_ 32
#define T_ 2048
#define N_ 2048
#define D_ 512
#define L_ 256
#define TE_ 1024
#define H_ 8
#define MROWS 65536  // B*T = B*N
#define KCH 16       // n-chunks for k softmax stats (= rows-per-b / 128)
#define NC_ 8        // n-chunks for attn partial accumulation

typedef __attribute__((ext_vector_type(8))) short short8;
typedef __attribute__((ext_vector_type(4))) float f32x4;
typedef __attribute__((ext_vector_type(4))) unsigned short us4;

__device__ __forceinline__ unsigned short f2bf(float f) {
  unsigned u = __float_as_uint(f);
  unsigned r = (u + 0x7FFF + ((u >> 16) & 1)) >> 16;  // RNE
  return (unsigned short)r;
}
__device__ __forceinline__ float bf2f(unsigned short u) {
  return __uint_as_float(((unsigned)u) << 16);
}
__device__ __forceinline__ void gload_lds16(const void* g, void* l) {
  __builtin_amdgcn_global_load_lds(
      (const __attribute__((address_space(1))) void*)g,
      (__attribute__((address_space(3))) void*)l, 16, 0, 0);
}

// ---------------- block reduce (256 threads) ----------------
__device__ __forceinline__ float blockReduceSum(float v, float* ws) {
#pragma unroll
  for (int m = 32; m >= 1; m >>= 1) v += __shfl_xor(v, m, 64);
  int wid = threadIdx.x >> 6;
  int lane = threadIdx.x & 63;
  __syncthreads();
  if (lane == 0) ws[wid] = v;
  __syncthreads();
  return ws[0] + ws[1] + ws[2] + ws[3];
}

// ---------------- row LayerNorm -> bf16 ----------------
template <int COLS>
__global__ void __launch_bounds__(256) ln_rows(const float* __restrict__ in,
                                               const float* __restrict__ g,
                                               const float* __restrict__ bb,
                                               unsigned short* __restrict__ out) {
  constexpr int E = COLS / 256;
  __shared__ float ws[4];
  size_t row = blockIdx.x;
  const float* rp = in + row * COLS;
  float v[E];
  float s = 0.f;
#pragma unroll
  for (int e = 0; e < E; ++e) {
    v[e] = rp[threadIdx.x + e * 256];
    s += v[e];
  }
  s = blockReduceSum(s, ws);
  float mean = s * (1.0f / COLS);
  float q = 0.f;
#pragma unroll
  for (int e = 0; e < E; ++e) {
    float d = v[e] - mean;
    q += d * d;
  }
  q = blockReduceSum(q, ws);
  float rstd = rsqrtf(q * (1.0f / COLS) + 1e-5f);
  unsigned short* op = out + row * COLS;
#pragma unroll
  for (int e = 0; e < E; ++e) {
    int c = threadIdx.x + e * 256;
    op[c] = f2bf((v[e] - mean) * rstd * g[c] + bb[c]);
  }
}

// ---------------- all weight transpose + casts in one launch ----------------
__global__ void __launch_bounds__(256) transcast_all(const float* __restrict__ Wq,
                                                     const float* __restrict__ Wk,
                                                     const float* __restrict__ Wv,
                                                     const float* __restrict__ Wo,
                                                     unsigned short* __restrict__ wqt,
                                                     unsigned short* __restrict__ wkt,
                                                     unsigned short* __restrict__ wvt,
                                                     unsigned short* __restrict__ wot) {
  int z = blockIdx.z;
  const float* W;
  unsigned short* Wt;
  int K;
  if (z == 0) { W = Wq; Wt = wqt; K = 512; }
  else if (z == 1) { W = Wk; Wt = wkt; K = 256; }
  else if (z == 2) { W = Wv; Wt = wvt; K = 256; }
  else { W = Wo; Wt = wot; K = 512; }
  int k0 = blockIdx.x * 32, n0 = blockIdx.y * 32;
  if (k0 >= K) return;
  __shared__ float t[32][33];
  int tx = threadIdx.x & 31, ty = threadIdx.x >> 5;  // 32 x 8
#pragma unroll
  for (int i = 0; i < 32; i += 8)
    t[ty + i][tx] = W[(size_t)(k0 + ty + i) * 512 + n0 + tx];
  __syncthreads();
#pragma unroll
  for (int i = 0; i < 32; i += 8)
    Wt[(size_t)(n0 + ty + i) * K + k0 + tx] = f2bf(t[tx][ty + i]);
}

// ---------------- bf16 MFMA GEMM: C[M,512] = A[M,KT] @ Wt[512,KT]^T + bias (+add) ----------------
// 128x128 tile, 4 waves in 2x2, each wave 64x64 as 4x4 of 16x16x32 MFMA. Double-buffered.
// XCD-aware block remap: all 4 n-blocks of one A-row-tile colocate on one XCD (L2 reuse).
// KSTATS: bf16 out + per-column (over the 128-row tile) softmax stats on the ROUNDED values.
template <int KT, bool ADD, bool OUTBF, bool KSTATS>
__global__ void __launch_bounds__(256) gemm_mfma(const unsigned short* __restrict__ A,
                                                 const unsigned short* __restrict__ Wt,
                                                 const float* __restrict__ bias,
                                                 const float* __restrict__ add,
                                                 void* __restrict__ Cv,
                                                 float* __restrict__ pmaxO,
                                                 float* __restrict__ psumO) {
  __shared__ __align__(16) unsigned short sA[2][128 * 32];
  __shared__ __align__(16) unsigned short sB[2][128 * 32];
  int tid = threadIdx.x;
  int w = tid >> 6, lane = tid & 63;
  int quad = lane >> 4, r16 = lane & 15;
  int wr = w >> 1, wc = w & 1;
  // remap: slot s (xcd = s%8 assumed) -> by in [xcd*64, xcd*64+64), bx = consecutive
  int s = blockIdx.x + (blockIdx.y << 2);  // grid (4,512), 2048 slots
  int xcd = s & 7, j = s >> 3;
  int by = xcd * 64 + (j >> 2);
  int bx = j & 3;
  size_t m0 = (size_t)by * 128;
  int n0 = bx * 128;
  int srow = lane >> 2;        // 0..15
  int scol = (lane & 3) * 8;   // ushort offset within 32-wide K slice
  f32x4 acc[4][4] = {};

  const unsigned short* Arow0 = &A[(m0 + w * 32 + srow) * KT + scol];
  const unsigned short* Brow0 = &Wt[(size_t)(n0 + w * 32 + srow) * KT + scol];

#define G_STAGE(buf, k0)                                                          \
  do {                                                                            \
    gload_lds16(Arow0 + (k0), &sA[buf][(w * 2 + 0) * 512]);                       \
    gload_lds16(Arow0 + (size_t)16 * KT + (k0), &sA[buf][(w * 2 + 1) * 512]);     \
    gload_lds16(Brow0 + (k0), &sB[buf][(w * 2 + 0) * 512]);                       \
    gload_lds16(Brow0 + (size_t)16 * KT + (k0), &sB[buf][(w * 2 + 1) * 512]);     \
  } while (0)

#define G_COMPUTE(buf)                                                            \
  do {                                                                            \
    short8 af[4], bfr[4];                                                         \
    _Pragma("unroll") for (int mi = 0; mi < 4; ++mi)                              \
        af[mi] = *(const short8*)&sA[buf][(wr * 64 + mi * 16 + r16) * 32 + quad * 8]; \
    _Pragma("unroll") for (int ni = 0; ni < 4; ++ni)                              \
        bfr[ni] = *(const short8*)&sB[buf][(wc * 64 + ni * 16 + r16) * 32 + quad * 8]; \
    _Pragma("unroll") for (int mi = 0; mi < 4; ++mi)                              \
        _Pragma("unroll") for (int ni = 0; ni < 4; ++ni)                          \
            acc[mi][ni] =                                                         \
                __builtin_amdgcn_mfma_f32_16x16x32_bf16(af[mi], bfr[ni], acc[mi][ni], 0, 0, 0); \
  } while (0)

  constexpr int NT = KT / 32;  // even (8 or 16)
  G_STAGE(0, 0);
  __syncthreads();
#pragma unroll 1
  for (int t = 0; t < NT; t += 2) {
    if (t + 1 < NT) G_STAGE(1, (t + 1) * 32);
    G_COMPUTE(0);
    __syncthreads();
    if (t + 2 < NT) G_STAGE(0, (t + 2) * 32);
    G_COMPUTE(1);
    __syncthreads();
  }
#undef G_STAGE
#undef G_COMPUTE

  float* Cf = (float*)Cv;
  unsigned short* Cb = (unsigned short*)Cv;

  if constexpr (KSTATS) {
    float tmax[4], tsum[4];
#pragma unroll
    for (int ni = 0; ni < 4; ++ni) { tmax[ni] = -1e30f; tsum[ni] = 0.f; }
    // pass 1: round, store, track max of the ROUNDED values
#pragma unroll
    for (int mi = 0; mi < 4; ++mi)
#pragma unroll
      for (int r = 0; r < 4; ++r) {
        size_t grow = m0 + wr * 64 + mi * 16 + quad * 4 + r;
#pragma unroll
        for (int ni = 0; ni < 4; ++ni) {
          int gcol = n0 + wc * 64 + ni * 16 + r16;
          unsigned short bv = f2bf(acc[mi][ni][r] + bias[gcol]);
          Cb[grow * 512 + gcol] = bv;
          tmax[ni] = fmaxf(tmax[ni], bf2f(bv));
        }
      }
    // pass 2: sum exp of rounded values
#pragma unroll
    for (int mi = 0; mi < 4; ++mi)
#pragma unroll
      for (int r = 0; r < 4; ++r)
#pragma unroll
        for (int ni = 0; ni < 4; ++ni) {
          int gcol = n0 + wc * 64 + ni * 16 + r16;
          float vr = bf2f(f2bf(acc[mi][ni][r] + bias[gcol]));
          tsum[ni] += expf(vr - tmax[ni]);
        }
    // reduce across quads (lanes xor 16, 32)
#pragma unroll
    for (int ni = 0; ni < 4; ++ni) {
#pragma unroll
      for (int mask = 16; mask <= 32; mask <<= 1) {
        float om = __shfl_xor(tmax[ni], mask, 64);
        float os = __shfl_xor(tsum[ni], mask, 64);
        float nm = fmaxf(tmax[ni], om);
        tsum[ni] = tsum[ni] * expf(tmax[ni] - nm) + os * expf(om - nm);
        tmax[ni] = nm;
      }
    }
    __shared__ float smax[4][64], ssum2[4][64];
    if (quad == 0) {
#pragma unroll
      for (int ni = 0; ni < 4; ++ni) {
        smax[w][ni * 16 + r16] = tmax[ni];
        ssum2[w][ni * 16 + r16] = tsum[ni];
      }
    }
    __syncthreads();
    if (w < 2 && quad == 0) {  // waves 0/1 combine with waves 2/3 (other row-half)
      int b = by >> 4, ch = by & 15;
#pragma unroll
      for (int ni = 0; ni < 4; ++ni) {
        int i = ni * 16 + r16;
        float m1 = smax[w][i], m2 = smax[w + 2][i];
        float s1 = ssum2[w][i], s2 = ssum2[w + 2][i];
        float nm = fmaxf(m1, m2);
        float ss = s1 * expf(m1 - nm) + s2 * expf(m2 - nm);
        size_t off = ((size_t)(b * KCH + ch)) * D_ + n0 + w * 64 + i;
        pmaxO[off] = nm;
        psumO[off] = ss;
      }
    }
  } else {
#pragma unroll
    for (int mi = 0; mi < 4; ++mi)
#pragma unroll
      for (int r = 0; r < 4; ++r) {
        size_t grow = m0 + wr * 64 + mi * 16 + quad * 4 + r;
#pragma unroll
        for (int ni = 0; ni < 4; ++ni) {
          int gcol = n0 + wc * 64 + ni * 16 + r16;
          float val = acc[mi][ni][r] + bias[gcol];
          if constexpr (ADD) val += add[grow * 512 + gcol];
          if constexpr (OUTBF)
            Cb[grow * 512 + gcol] = f2bf(val);
          else
            Cf[grow * 512 + gcol] = val;
        }
      }
  }
}

// ---------------- attn_part[b,h,nc] = softmax(k)^T @ v over an n-chunk of 256 ----------------
// bf16 k/v inputs; global stats combined in prologue from per-chunk partials.
__global__ void __launch_bounds__(256) attn_part_kernel(const unsigned short* __restrict__ k,
                                                        const unsigned short* __restrict__ v,
                                                        const float* __restrict__ pmax,
                                                        const float* __restrict__ psum,
                                                        float* __restrict__ part) {
  int b = blockIdx.x, h = blockIdx.y, nc = blockIdx.z;
  int tid = threadIdx.x;
  __shared__ float ks_[32][68];
  __shared__ float vs_[32][68];
  __shared__ float mx[64], is_[64];
  int lr = tid >> 4;
  int c4 = (tid & 15) * 4;
  const unsigned short* kp = k + ((size_t)b * N_ + nc * 256) * D_ + h * 64;
  const unsigned short* vp = v + ((size_t)b * N_ + nc * 256) * D_ + h * 64;
  us4 kv0 = *(const us4*)&kp[(size_t)lr * D_ + c4];
  us4 vv0 = *(const us4*)&vp[(size_t)lr * D_ + c4];
  us4 kv1 = *(const us4*)&kp[(size_t)(lr + 16) * D_ + c4];
  us4 vv1 = *(const us4*)&vp[(size_t)(lr + 16) * D_ + c4];
  if (tid < 64) {
    int c = h * 64 + tid;
    float m = -1e30f, s = 0.f;
#pragma unroll
    for (int ch = 0; ch < KCH; ++ch) {
      float pm = pmax[((size_t)(b * KCH + ch)) * D_ + c];
      float ps = psum[((size_t)(b * KCH + ch)) * D_ + c];
      float nm = fmaxf(m, pm);
      s = s * expf(m - nm) + ps * expf(pm - nm);
      m = nm;
    }
    mx[tid] = m;
    is_[tid] = 1.f / s;
  }
  float acc[4][4] = {};
  int tx = tid & 15, ty = tid >> 4;
  for (int n0 = 0; n0 < 256; n0 += 32) {
    __syncthreads();  // prev compute done; also publishes mx/is_ on first pass
#pragma unroll
    for (int j = 0; j < 4; ++j) {
      ks_[lr][c4 + j] = expf(bf2f(kv0[j]) - mx[c4 + j]) * is_[c4 + j];
      vs_[lr][c4 + j] = bf2f(vv0[j]);
      ks_[lr + 16][c4 + j] = expf(bf2f(kv1[j]) - mx[c4 + j]) * is_[c4 + j];
      vs_[lr + 16][c4 + j] = bf2f(vv1[j]);
    }
    if (n0 + 32 < 256) {  // prefetch next chunk under compute
      kv0 = *(const us4*)&kp[(size_t)(n0 + 32 + lr) * D_ + c4];
      vv0 = *(const us4*)&vp[(size_t)(n0 + 32 + lr) * D_ + c4];
      kv1 = *(const us4*)&kp[(size_t)(n0 + 48 + lr) * D_ + c4];
      vv1 = *(const us4*)&vp[(size_t)(n0 + 48 + lr) * D_ + c4];
    }
    __syncthreads();
#pragma unroll
    for (int nn = 0; nn < 32; ++nn) {
      float av[4], bv2[4];
#pragma unroll
      for (int i = 0; i < 4; ++i) av[i] = ks_[nn][ty * 4 + i];
#pragma unroll
      for (int j = 0; j < 4; ++j) bv2[j] = vs_[nn][tx * 4 + j];
#pragma unroll
      for (int i = 0; i < 4; ++i)
#pragma unroll
        for (int j = 0; j < 4; ++j) acc[i][j] += av[i] * bv2[j];
    }
  }
  float* ap = part + ((size_t)(b * H_ + h) * NC_ + nc) * 4096;
#pragma unroll
  for (int i = 0; i < 4; ++i) {
    float4 st = make_float4(acc[i][0], acc[i][1], acc[i][2], acc[i][3]);
    *(float4*)&ap[(ty * 4 + i) * 64 + tx * 4] = st;
  }
}

// ---------------- reduce NC_ partials -> attnT (bf16, transposed: [l][d]) ----------------
__global__ void __launch_bounds__(256) attn_reduce(const float* __restrict__ part,
                                                   unsigned short* __restrict__ attnT) {
  size_t o = ((size_t)blockIdx.x * 256 + threadIdx.x) * 4;  // 1M elements total
  size_t bh = o >> 12;
  size_t e = o & 4095;
  float4 s = make_float4(0.f, 0.f, 0.f, 0.f);
#pragma unroll
  for (int nc = 0; nc < NC_; ++nc) {
    float4 p = *(const float4*)&part[(bh * NC_ + nc) * 4096 + e];
    s.x += p.x;
    s.y += p.y;
    s.z += p.z;
    s.w += p.w;
  }
  // part element e = d*64 + l  (attn[d][l]); emit attnT[l][d] in bf16
  int d = (int)(e >> 6);
  int l = (int)(e & 63);
  unsigned short* ab = attnT + bh * 4096;
  ab[(l + 0) * 64 + d] = f2bf(s.x);
  ab[(l + 1) * 64 + d] = f2bf(s.y);
  ab[(l + 2) * 64 + d] = f2bf(s.z);
  ab[(l + 3) * 64 + d] = f2bf(s.w);
}

// ---------------- emb modulation: eo = silu(emb) @ We + be ----------------
__global__ void __launch_bounds__(256) embmod(const float* __restrict__ emb,
                                              const float* __restrict__ We,
                                              const float* __restrict__ be,
                                              float* __restrict__ eo) {
  int b = blockIdx.x, tid = threadIdx.x;
  __shared__ float se[TE_];
  for (int i = tid; i < TE_; i += 256) {
    float e = emb[b * TE_ + i];
    se[i] = e / (1.f + expf(-e));
  }
  __syncthreads();
  int j0 = tid * 4;
  float a0 = 0, a1 = 0, a2 = 0, a3 = 0;
  for (int i = 0; i < TE_; ++i) {
    float s = se[i];
    float4 wv = *(const float4*)&We[(size_t)i * 1024 + j0];
    a0 += s * wv.x;
    a1 += s * wv.y;
    a2 += s * wv.z;
    a3 += s * wv.w;
  }
  eo[b * 1024 + j0 + 0] = a0 + be[j0 + 0];
  eo[b * 1024 + j0 + 1] = a1 + be[j0 + 1];
  eo[b * 1024 + j0 + 2] = a2 + be[j0 + 2];
  eo[b * 1024 + j0 + 3] = a3 + be[j0 + 3];
}

// ---------------- y = softmax(q) @ attnT^T via MFMA, softmax fused per-lane ----------------
// Per block: 256 q-rows x 64 cols (one head). After staging, thread t owns row t:
// full softmax in-lane (no cross-lane ops); exp values written back to LDS as bf16;
// 1/sum applied as a row scale in the epilogue (commutes through the GEMM).
__global__ void __launch_bounds__(256) yein_mfma(const unsigned short* __restrict__ q,
                                                 const unsigned short* __restrict__ attnT,
                                                 float* __restrict__ y) {
  int b = blockIdx.z, h = blockIdx.y;
  size_t t0 = (size_t)blockIdx.x * 256;
  int tid = threadIdx.x;
  int w = tid >> 6, lane = tid & 63;
  int quad = lane >> 4, r16 = lane & 15;
  int srow = lane >> 2;
  int scol = (lane & 3) * 8;
  __shared__ __align__(16) unsigned short sA[2][256 * 32];  // 32 KB
  __shared__ __align__(16) unsigned short sB[2][64 * 32];   // 8 KB
  __shared__ float inv_s[256];
  const unsigned short* qp = q + ((size_t)b * T_ + t0) * D_ + h * 64;
  const unsigned short* bp = attnT + (size_t)(b * H_ + h) * 4096;
  f32x4 acc[4][4] = {};

#pragma unroll
  for (int half = 0; half < 2; ++half) {
    int k0 = half * 32;
#pragma unroll
    for (int i = 0; i < 4; ++i) {
      int seg = w * 4 + i;  // 0..15, 16 rows each
      gload_lds16(&qp[(size_t)(seg * 16 + srow) * D_ + k0 + scol], &sA[half][seg * 512]);
    }
    gload_lds16(&bp[(w * 16 + srow) * 64 + k0 + scol], &sB[half][w * 512]);
  }
  __syncthreads();

  // fused per-lane softmax on row tid
  {
    int r = tid;
    float vals[64];
#pragma unroll
    for (int hf = 0; hf < 2; ++hf)
#pragma unroll
      for (int blk = 0; blk < 4; ++blk) {
        short8 vv = *(const short8*)&sA[hf][r * 32 + blk * 8];
#pragma unroll
        for (int jj = 0; jj < 8; ++jj)
          vals[hf * 32 + blk * 8 + jj] = bf2f((unsigned short)vv[jj]);
      }
    float m = vals[0];
#pragma unroll
    for (int i = 1; i < 64; ++i) m = fmaxf(m, vals[i]);
    float ssum = 0.f;
#pragma unroll
    for (int i = 0; i < 64; ++i) {
      vals[i] = expf(vals[i] - m);
      ssum += vals[i];
    }
    inv_s[r] = 1.f / ssum;
#pragma unroll
    for (int hf = 0; hf < 2; ++hf)
#pragma unroll
      for (int blk = 0; blk < 4; ++blk) {
        short8 vv;
#pragma unroll
        for (int jj = 0; jj < 8; ++jj)
          vv[jj] = (short)f2bf(vals[hf * 32 + blk * 8 + jj]);
        *(short8*)&sA[hf][r * 32 + blk * 8] = vv;
      }
  }
  __syncthreads();

#pragma unroll
  for (int half = 0; half < 2; ++half) {
    short8 af[4], bfr[4];
#pragma unroll
    for (int mi = 0; mi < 4; ++mi)
      af[mi] = *(const short8*)&sA[half][(w * 64 + mi * 16 + r16) * 32 + quad * 8];
#pragma unroll
    for (int ni = 0; ni < 4; ++ni)
      bfr[ni] = *(const short8*)&sB[half][(ni * 16 + r16) * 32 + quad * 8];
#pragma unroll
    for (int mi = 0; mi < 4; ++mi)
#pragma unroll
      for (int ni = 0; ni < 4; ++ni)
        acc[mi][ni] = __builtin_amdgcn_mfma_f32_16x16x32_bf16(af[mi], bfr[ni], acc[mi][ni], 0, 0, 0);
  }

#pragma unroll
  for (int mi = 0; mi < 4; ++mi)
#pragma unroll
    for (int r = 0; r < 4; ++r) {
      int lrow = w * 64 + mi * 16 + quad * 4 + r;
      float sc = inv_s[lrow];  // same addr across 16-lane group: LDS broadcast
      size_t grow = t0 + lrow;
      float* yp = y + ((size_t)b * T_ + grow) * D_ + h * 64;
#pragma unroll
      for (int ni = 0; ni < 4; ++ni) yp[ni * 16 + r16] = acc[mi][ni][r] * sc;
    }
}

// ---------------- LN(y) * (1+scale) + shift, then silu -> bf16 ----------------
__global__ void __launch_bounds__(256) modln(const float* __restrict__ y,
                                             const float* __restrict__ sg,
                                             const float* __restrict__ sb,
                                             const float* __restrict__ eo,
                                             unsigned short* __restrict__ hs) {
  __shared__ float ws[4];
  size_t row = blockIdx.x;
  int b = (int)(row >> 11);
  const float* rp = y + row * D_;
  float v[2];
  float s = 0.f;
#pragma unroll
  for (int e = 0; e < 2; ++e) {
    v[e] = rp[threadIdx.x + e * 256];
    s += v[e];
  }
  s = blockReduceSum(s, ws);
  float mean = s * (1.0f / D_);
  float q = 0.f;
#pragma unroll
  for (int e = 0; e < 2; ++e) {
    float d = v[e] - mean;
    q += d * d;
  }
  q = blockReduceSum(q, ws);
  float rstd = rsqrtf(q * (1.0f / D_) + 1e-5f);
#pragma unroll
  for (int e = 0; e < 2; ++e) {
    int c = threadIdx.x + e * 256;
    float xm = (v[e] - mean) * rstd * sg[c] + sb[c];
    float sc = eo[b * 1024 + c];
    float sh = eo[b * 1024 + D_ + c];
    float hm = xm * (1.f + sc) + sh;
    hs[row * D_ + c] = f2bf(hm / (1.f + expf(-hm)));
  }
}

extern "C" void kernel_launch(void* const* d_in, const int* in_sizes, int n_in,
                              void* d_out, int out_size, void* d_ws, size_t ws_size,
                              hipStream_t stream) {
  const float* x = (const float*)d_in[0];
  const float* xf = (const float*)d_in[1];
  const float* emb = (const float*)d_in[2];
  const float* norm_g = (const float*)d_in[3];
  const float* norm_b = (const float*)d_in[4];
  const float* tnorm_g = (const float*)d_in[5];
  const float* tnorm_b = (const float*)d_in[6];
  const float* Wq = (const float*)d_in[7];
  const float* bq = (const float*)d_in[8];
  const float* Wk = (const float*)d_in[9];
  const float* bk = (const float*)d_in[10];
  const float* Wv = (const float*)d_in[11];
  const float* bv = (const float*)d_in[12];
  const float* We = (const float*)d_in[13];
  const float* be = (const float*)d_in[14];
  const float* sg = (const float*)d_in[15];
  const float* sb = (const float*)d_in[16];
  const float* Wo = (const float*)d_in[17];
  const float* bo = (const float*)d_in[18];
  float* out = (float*)d_out;

  float* w = (float*)d_ws;
  // layout (float offsets):
  unsigned short* qbf = (unsigned short*)w;                  // 33.5M ushort
  unsigned short* kb = (unsigned short*)(w + 16777216);      // 33.5M ushort (bf16 k)
  unsigned short* vb = (unsigned short*)(w + 33554432);      // 33.5M ushort (bf16 v)
  float* ybuf = w + 50331648;                                // 33.5M floats (y)
  unsigned short* xnbf = (unsigned short*)(w + 83886080);    // 33.5M ushort (xn -> hs)
  unsigned short* xfnbf = (unsigned short*)(w + 100663296);  // 16.78M ushort
  float* attnpart = w + 100663296;                           // reuse xfn region (8.39M floats)
  unsigned short* attnT = (unsigned short*)(w + 109051904);  // 1.05M ushort
  float* pmaxp = w + 109051904 + 524288;                     // 262144 floats
  float* psump = pmaxp + 262144;                             // 262144
  float* embout = psump + 262144;                            // 32768
  unsigned short* wqt = (unsigned short*)(embout + 32768);   // 512*512
  unsigned short* wkt = wqt + 262144;                        // 512*256
  unsigned short* wvt = wkt + 131072;                        // 512*256
  unsigned short* wot = wvt + 131072;                        // 512*512

  // 0. all weight transpose-casts (one launch)
  transcast_all<<<dim3(16, 16, 4), 256, 0, stream>>>(Wq, Wk, Wv, Wo, wqt, wkt, wvt, wot);
  // 1. xn = LN(x) -> bf16
  ln_rows<512><<<MROWS, 256, 0, stream>>>(x, norm_g, norm_b, xnbf);
  // 2. q = xn @ Wq + bq -> bf16 (raw; softmax fused into yein)
  gemm_mfma<512, false, true, false><<<dim3(4, 512), 256, 0, stream>>>(
      xnbf, wqt, bq, nullptr, qbf, nullptr, nullptr);
  // 3. xfn = LN(xf) -> bf16
  ln_rows<256><<<MROWS, 256, 0, stream>>>(xf, tnorm_g, tnorm_b, xfnbf);
  // 4. k = xfn @ Wk + bk -> bf16 + fused per-chunk softmax stats (on rounded values)
  gemm_mfma<256, false, true, true><<<dim3(4, 512), 256, 0, stream>>>(
      xfnbf, wkt, bk, nullptr, kb, pmaxp, psump);
  // 5. v = xfn @ Wv + bv -> bf16
  gemm_mfma<256, false, true, false><<<dim3(4, 512), 256, 0, stream>>>(
      xfnbf, wvt, bv, nullptr, vb, nullptr, nullptr);
  // 6. attn partials (stats combined in prologue) + reduce -> attnT bf16
  attn_part_kernel<<<dim3(32, 8, NC_), 256, 0, stream>>>(kb, vb, pmaxp, psump, attnpart);
  attn_reduce<<<1024, 256, 0, stream>>>(attnpart, attnT);
  // 7. emb modulation
  embmod<<<32, 256, 0, stream>>>(emb, We, be, embout);
  // 8. y = softmax(q) @ attn -> ybuf via MFMA (softmax fused, per-lane rows)
  yein_mfma<<<dim3(8, 8, 32), 256, 0, stream>>>(qbf, attnT, ybuf);
  // 9. hs = silu(LN(y)*(1+scale)+shift) -> bf16 into xnbf (xn dead)
  modln<<<MROWS, 256, 0, stream>>>(ybuf, sg, sb, embout, xnbf);
  // 10. out = hs @ Wo + bo + x
  gemm_mfma<512, true, false, false><<<dim3(4, 512), 256, 0, stream>>>(
      xnbf, wot, bo, x, out, nullptr, nullptr);
}